// Round 1
// baseline (1805.407 us; speedup 1.0000x reference)
//
#include <hip/hip_runtime.h>
#include <hip/hip_bf16.h>
#include <math.h>

// Problem constants
#define BATCH 2
#define SEQ   2048
#define DMODEL 1024
#define NHEADS 16
#define DHEAD 64
#define MROWS (BATCH*SEQ)   // 4096

// ---------------- GEMM: C[m][n] = (sum_k A[m][k]*W[k][n] + bias[n]) * scale ----------------
// mode 0: scatter write to [B,H,S,dh] layout (for q/k/v)
// mode 1: row-major [M,N] write (final output / attn-out)
#define TILE 64
#define BKK  16

__global__ __launch_bounds__(256) void gemm_kernel(
    const float* __restrict__ A, const float* __restrict__ W,
    const float* __restrict__ bias, float* __restrict__ out,
    int M, int K, int N, int mode, float scale)
{
    __shared__ float As[BKK][TILE + 1];   // [k][m], padded
    __shared__ float Bs[BKK][TILE];       // [k][n]

    const int tid = threadIdx.x;
    const int tx = tid & 15;        // 0..15 -> 4 output cols
    const int ty = tid >> 4;        // 0..15 -> 4 output rows
    const int m0 = blockIdx.y * TILE;
    const int n0 = blockIdx.x * TILE;

    float acc[4][4] = {};

    for (int k0 = 0; k0 < K; k0 += BKK) {
        // A tile: 64 rows x 16 k-cols. Each thread: 4 elems, same k different row.
        {
            const int col = tid & 15;
            const int rbase = (tid >> 4) * 4;
            #pragma unroll
            for (int i = 0; i < 4; ++i) {
                const int r = rbase + i;
                As[col][r] = A[(size_t)(m0 + r) * K + (k0 + col)];
            }
        }
        // W tile: 16 k-rows x 64 cols. Coalesced in n.
        {
            const int col = tid & 63;
            const int rb  = tid >> 6;   // 0..3
            #pragma unroll
            for (int i = 0; i < 4; ++i) {
                const int r = rb + i * 4;
                Bs[r][col] = W[(size_t)(k0 + r) * N + (n0 + col)];
            }
        }
        __syncthreads();

        #pragma unroll
        for (int kk = 0; kk < BKK; ++kk) {
            float a[4], b[4];
            #pragma unroll
            for (int i = 0; i < 4; ++i) a[i] = As[kk][ty * 4 + i];
            #pragma unroll
            for (int j = 0; j < 4; ++j) b[j] = Bs[kk][tx * 4 + j];
            #pragma unroll
            for (int i = 0; i < 4; ++i)
                #pragma unroll
                for (int j = 0; j < 4; ++j)
                    acc[i][j] += a[i] * b[j];
        }
        __syncthreads();
    }

    #pragma unroll
    for (int i = 0; i < 4; ++i) {
        const int m = m0 + ty * 4 + i;
        #pragma unroll
        for (int j = 0; j < 4; ++j) {
            const int n = n0 + tx * 4 + j;
            const float c = (acc[i][j] + bias[n]) * scale;
            if (mode == 0) {
                // m -> (b, s); n -> (h, d). out layout [B,H,S,dh]
                const int b = m >> 11;          // /SEQ
                const int s = m & (SEQ - 1);
                const int h = n >> 6;           // /DHEAD
                const int d = n & (DHEAD - 1);
                out[((size_t)(b * NHEADS + h) * SEQ + s) * DHEAD + d] = c;
            } else {
                out[(size_t)m * N + n] = c;
            }
        }
    }
}

// ---------------- Flash attention (fp32, online softmax) ----------------
// Q pre-scaled by 1/sqrt(dh). pH ignored: constant shift across a softmax row.
// One block = 256 threads = 4 waves; each wave handles 4 queries (16 q/block).
// Writes O directly in [B,S,D] layout for the final projection.
#define AQ 16   // queries per block

__global__ __launch_bounds__(256) void attn_kernel(
    const float* __restrict__ Qg, const float* __restrict__ Kg,
    const float* __restrict__ Vg, float* __restrict__ Og)
{
    __shared__ float Ks[64][65];
    __shared__ float Vs[64][65];
    __shared__ float qs[AQ][64];
    __shared__ float ps[AQ][64];

    const int tid  = threadIdx.x;
    const int lane = tid & 63;
    const int w    = tid >> 6;                 // wave 0..3
    const int nqb  = SEQ / AQ;                 // 128 query-blocks per (b,h)
    const int qblk = blockIdx.x & (nqb - 1);
    const int bh   = blockIdx.x >> 7;          // /128
    const int q0   = qblk * AQ;

    const size_t base = (size_t)bh * SEQ * DHEAD;

    // stage the 16 query rows (already scaled)
    for (int t = tid; t < AQ * 64; t += 256) {
        const int r = t >> 6, d = t & 63;
        qs[r][d] = Qg[base + (size_t)(q0 + r) * DHEAD + d];
    }

    float m_run[4], l_run[4], o[4];
    #pragma unroll
    for (int qi = 0; qi < 4; ++qi) { m_run[qi] = -INFINITY; l_run[qi] = 0.f; o[qi] = 0.f; }

    for (int kb = 0; kb < SEQ; kb += 64) {
        __syncthreads();   // protect Ks/Vs (and first-iter qs) across waves
        for (int t = tid; t < 64 * 64; t += 256) {
            const int r = t >> 6, d = t & 63;
            Ks[r][d] = Kg[base + (size_t)(kb + r) * DHEAD + d];
            Vs[r][d] = Vg[base + (size_t)(kb + r) * DHEAD + d];
        }
        __syncthreads();

        // scores: lane = key index within this 64-key block
        float s[4] = {0.f, 0.f, 0.f, 0.f};
        #pragma unroll 16
        for (int d = 0; d < 64; ++d) {
            const float kd = Ks[lane][d];
            #pragma unroll
            for (int qi = 0; qi < 4; ++qi)
                s[qi] += qs[w * 4 + qi][d] * kd;
        }

        // online softmax per query
        float p[4];
        #pragma unroll
        for (int qi = 0; qi < 4; ++qi) {
            float mb = s[qi];
            #pragma unroll
            for (int off = 32; off >= 1; off >>= 1)
                mb = fmaxf(mb, __shfl_xor(mb, off, 64));
            const float m_new = fmaxf(m_run[qi], mb);
            const float alpha = __expf(m_run[qi] - m_new);
            p[qi] = __expf(s[qi] - m_new);
            float ls = p[qi];
            #pragma unroll
            for (int off = 32; off >= 1; off >>= 1)
                ls += __shfl_xor(ls, off, 64);
            l_run[qi] = l_run[qi] * alpha + ls;
            o[qi] *= alpha;
            m_run[qi] = m_new;
            ps[w * 4 + qi][lane] = p[qi];   // wave-local LDS round-trip (no cross-wave dep)
        }

        // PV: lane = output dim d
        #pragma unroll 8
        for (int l = 0; l < 64; ++l) {
            const float vv = Vs[l][lane];
            #pragma unroll
            for (int qi = 0; qi < 4; ++qi)
                o[qi] += ps[w * 4 + qi][l] * vv;
        }
    }

    // write O in [B,S,D] layout: out[((b*S+q)*H + h)*dh + d]
    const int b = bh >> 4, h = bh & 15;
    #pragma unroll
    for (int qi = 0; qi < 4; ++qi) {
        const int q = q0 + w * 4 + qi;
        Og[(((size_t)(b * SEQ + q) * NHEADS) + h) * DHEAD + lane] = o[qi] / l_run[qi];
    }
}

// ---------------- launch ----------------
extern "C" void kernel_launch(void* const* d_in, const int* in_sizes, int n_in,
                              void* d_out, int out_size, void* d_ws, size_t ws_size,
                              hipStream_t stream) {
    const float* x  = (const float*)d_in[0];
    // d_in[1] = pH : softmax shift-invariant, ignored
    const float* Wq = (const float*)d_in[2];
    const float* bq = (const float*)d_in[3];
    const float* Wk = (const float*)d_in[4];
    const float* bk = (const float*)d_in[5];
    const float* Wv = (const float*)d_in[6];
    const float* bv = (const float*)d_in[7];
    const float* Wo = (const float*)d_in[8];
    const float* bo = (const float*)d_in[9];
    float* out = (float*)d_out;

    float* ws = (float*)d_ws;
    const size_t SZ = (size_t)MROWS * DMODEL;  // 4M floats = 16 MB
    float* q  = ws;
    float* k  = ws + SZ;
    float* v  = ws + 2 * SZ;
    float* ao = ws + 3 * SZ;

    dim3 gemm_grid(DMODEL / TILE, MROWS / TILE);  // (16, 64)
    dim3 blk(256);

    const float qscale = 0.125f;  // 1/sqrt(64)
    hipLaunchKernelGGL(gemm_kernel, gemm_grid, blk, 0, stream,
                       x, Wq, bq, q, MROWS, DMODEL, DMODEL, 0, qscale);
    hipLaunchKernelGGL(gemm_kernel, gemm_grid, blk, 0, stream,
                       x, Wk, bk, k, MROWS, DMODEL, DMODEL, 0, 1.0f);
    hipLaunchKernelGGL(gemm_kernel, gemm_grid, blk, 0, stream,
                       x, Wv, bv, v, MROWS, DMODEL, DMODEL, 0, 1.0f);

    dim3 attn_grid(BATCH * NHEADS * (SEQ / AQ));  // 4096
    hipLaunchKernelGGL(attn_kernel, attn_grid, blk, 0, stream, q, k, v, ao);

    hipLaunchKernelGGL(gemm_kernel, gemm_grid, blk, 0, stream,
                       ao, Wo, bo, out, MROWS, DMODEL, DMODEL, 1, 1.0f);
}

// Round 2
// 947.659 us; speedup vs baseline: 1.9051x; 1.9051x over previous
//
#include <hip/hip_runtime.h>
#include <hip/hip_bf16.h>
#include <math.h>

// Problem constants
#define BATCH 2
#define SEQ   2048
#define DMODEL 1024
#define NHEADS 16
#define DHEAD 64
#define MROWS (BATCH*SEQ)   // 4096

typedef __attribute__((ext_vector_type(8))) short bf16x8;
typedef __attribute__((ext_vector_type(4))) short bf16x4;
typedef __attribute__((ext_vector_type(4))) float f32x4;

__device__ __forceinline__ short f2bf(float f) {   // RNE float->bf16
    union { float f; unsigned u; } c; c.f = f;
    unsigned r = (c.u + 0x7fffu + ((c.u >> 16) & 1u)) >> 16;
    return (short)r;
}
__device__ __forceinline__ float bf2f(short h) {
    union { unsigned u; float f; } c; c.u = ((unsigned)(unsigned short)h) << 16;
    return c.f;
}

// ---------------- GEMM (fp32 VALU, unchanged from R1) ----------------
#define TILE 64
#define BKK  16

__global__ __launch_bounds__(256) void gemm_kernel(
    const float* __restrict__ A, const float* __restrict__ W,
    const float* __restrict__ bias, float* __restrict__ out,
    int M, int K, int N, int mode, float scale)
{
    __shared__ float As[BKK][TILE + 1];
    __shared__ float Bs[BKK][TILE];

    const int tid = threadIdx.x;
    const int tx = tid & 15;
    const int ty = tid >> 4;
    const int m0 = blockIdx.y * TILE;
    const int n0 = blockIdx.x * TILE;

    float acc[4][4] = {};

    for (int k0 = 0; k0 < K; k0 += BKK) {
        {
            const int col = tid & 15;
            const int rbase = (tid >> 4) * 4;
            #pragma unroll
            for (int i = 0; i < 4; ++i) {
                const int r = rbase + i;
                As[col][r] = A[(size_t)(m0 + r) * K + (k0 + col)];
            }
        }
        {
            const int col = tid & 63;
            const int rb  = tid >> 6;
            #pragma unroll
            for (int i = 0; i < 4; ++i) {
                const int r = rb + i * 4;
                Bs[r][col] = W[(size_t)(k0 + r) * N + (n0 + col)];
            }
        }
        __syncthreads();

        #pragma unroll
        for (int kk = 0; kk < BKK; ++kk) {
            float a[4], b[4];
            #pragma unroll
            for (int i = 0; i < 4; ++i) a[i] = As[kk][ty * 4 + i];
            #pragma unroll
            for (int j = 0; j < 4; ++j) b[j] = Bs[kk][tx * 4 + j];
            #pragma unroll
            for (int i = 0; i < 4; ++i)
                #pragma unroll
                for (int j = 0; j < 4; ++j)
                    acc[i][j] += a[i] * b[j];
        }
        __syncthreads();
    }

    #pragma unroll
    for (int i = 0; i < 4; ++i) {
        const int m = m0 + ty * 4 + i;
        #pragma unroll
        for (int j = 0; j < 4; ++j) {
            const int n = n0 + tx * 4 + j;
            const float c = (acc[i][j] + bias[n]) * scale;
            if (mode == 0) {
                const int b = m >> 11;
                const int s = m & (SEQ - 1);
                const int h = n >> 6;
                const int d = n & (DHEAD - 1);
                out[((size_t)(b * NHEADS + h) * SEQ + s) * DHEAD + d] = c;
            } else {
                out[(size_t)m * N + n] = c;
            }
        }
    }
}

// ---------------- MFMA flash attention (bf16 hi/lo split, online softmax) ----------------
// Q pre-scaled by (1/sqrt(dh))*log2(e) in the GEMM; softmax done base-2.
// pH ignored (constant shift across each softmax row).
// Block = 256 thr = 4 waves; wave handles 16 queries; block covers 64 queries.
// K-loop: 64 keys/iter staged to LDS as bf16 hi+lo; V staged transposed.
#define PADB 72   // padded row length (shorts): 144 B = 9*16 B

__global__ __launch_bounds__(256) void attn_mfma(
    const float* __restrict__ Qg, const float* __restrict__ Kg,
    const float* __restrict__ Vg, float* __restrict__ Og)
{
    __shared__ short Khi[64 * PADB], Klo[64 * PADB];   // [key][d]
    __shared__ short Vhi[64 * PADB], Vlo[64 * PADB];   // transposed: [d][key]
    __shared__ short Ph[4][16 * PADB], Pl[4][16 * PADB]; // per-wave P tiles [row][key]

    const int tid  = threadIdx.x;
    const int lane = tid & 63;
    const int w    = tid >> 6;
    const int quad = lane >> 4;
    const int l15  = lane & 15;

    const int qtile = blockIdx.x & 31;       // 32 q-tiles of 64
    const int bh    = blockIdx.x >> 5;       // 0..31
    const int q0    = qtile * 64 + w * 16;
    const size_t base = (size_t)bh * SEQ * DHEAD;

    // ---- Q fragments (A-operand layout), hi/lo split ----
    bf16x8 qhi[2], qlo[2];
    {
        const float* qrow = Qg + base + (size_t)(q0 + l15) * DHEAD;
        #pragma unroll
        for (int h = 0; h < 2; ++h) {
            const int d0 = h * 32 + quad * 8;
            float4 v0 = *(const float4*)(qrow + d0);
            float4 v1 = *(const float4*)(qrow + d0 + 4);
            float vv[8] = {v0.x, v0.y, v0.z, v0.w, v1.x, v1.y, v1.z, v1.w};
            #pragma unroll
            for (int j = 0; j < 8; ++j) {
                short hi = f2bf(vv[j]);
                qhi[h][j] = hi;
                qlo[h][j] = f2bf(vv[j] - bf2f(hi));
            }
        }
    }

    f32x4 o[4] = {};
    float m_run[4], l_run[4];
    #pragma unroll
    for (int r = 0; r < 4; ++r) { m_run[r] = -INFINITY; l_run[r] = 0.f; }

    for (int kb = 0; kb < SEQ; kb += 64) {
        __syncthreads();   // protect K/V LDS from previous iteration's readers
        // ---- stage K (row-major) and V (transposed), hi/lo bf16 ----
        #pragma unroll
        for (int i = 0; i < 4; ++i) {
            const int r = (tid >> 4) + i * 16;   // key row 0..63
            const int c = (tid & 15) * 4;        // d col 0,4,..,60
            float4 kv = *(const float4*)(Kg + base + (size_t)(kb + r) * DHEAD + c);
            float kf[4] = {kv.x, kv.y, kv.z, kv.w};
            bf16x4 kh, kl;
            #pragma unroll
            for (int j = 0; j < 4; ++j) {
                short hi = f2bf(kf[j]); kh[j] = hi; kl[j] = f2bf(kf[j] - bf2f(hi));
            }
            *(bf16x4*)(Khi + r * PADB + c) = kh;
            *(bf16x4*)(Klo + r * PADB + c) = kl;

            float4 vv = *(const float4*)(Vg + base + (size_t)(kb + r) * DHEAD + c);
            float vf[4] = {vv.x, vv.y, vv.z, vv.w};
            #pragma unroll
            for (int j = 0; j < 4; ++j) {
                short hi = f2bf(vf[j]);
                Vhi[(c + j) * PADB + r] = hi;
                Vlo[(c + j) * PADB + r] = f2bf(vf[j] - bf2f(hi));
            }
        }
        __syncthreads();

        // ---- S = Q K^T via MFMA (3-term hi/lo) ----
        f32x4 sc[4] = {};
        #pragma unroll
        for (int nf = 0; nf < 4; ++nf) {
            const short* kb_hi = Khi + (nf * 16 + l15) * PADB + quad * 8;
            const short* kb_lo = Klo + (nf * 16 + l15) * PADB + quad * 8;
            bf16x8 kh0 = *(const bf16x8*)(kb_hi);
            bf16x8 kh1 = *(const bf16x8*)(kb_hi + 32);
            bf16x8 kl0 = *(const bf16x8*)(kb_lo);
            bf16x8 kl1 = *(const bf16x8*)(kb_lo + 32);
            f32x4 c = sc[nf];
            c = __builtin_amdgcn_mfma_f32_16x16x32_bf16(qhi[0], kh0, c, 0, 0, 0);
            c = __builtin_amdgcn_mfma_f32_16x16x32_bf16(qhi[1], kh1, c, 0, 0, 0);
            c = __builtin_amdgcn_mfma_f32_16x16x32_bf16(qlo[0], kh0, c, 0, 0, 0);
            c = __builtin_amdgcn_mfma_f32_16x16x32_bf16(qlo[1], kh1, c, 0, 0, 0);
            c = __builtin_amdgcn_mfma_f32_16x16x32_bf16(qhi[0], kl0, c, 0, 0, 0);
            c = __builtin_amdgcn_mfma_f32_16x16x32_bf16(qhi[1], kl1, c, 0, 0, 0);
            sc[nf] = c;
        }

        // ---- online softmax (base-2); C-layout row = quad*4+r ----
        float alpha[4];
        #pragma unroll
        for (int r = 0; r < 4; ++r) {
            float mb = fmaxf(fmaxf(sc[0][r], sc[1][r]), fmaxf(sc[2][r], sc[3][r]));
            #pragma unroll
            for (int off = 8; off >= 1; off >>= 1)
                mb = fmaxf(mb, __shfl_xor(mb, off, 64));
            const float m_new = fmaxf(m_run[r], mb);
            alpha[r] = exp2f(m_run[r] - m_new);
            m_run[r] = m_new;
            float ls = 0.f;
            #pragma unroll
            for (int nf = 0; nf < 4; ++nf) {
                float p = exp2f(sc[nf][r] - m_new);
                sc[nf][r] = p;
                ls += p;
            }
            #pragma unroll
            for (int off = 8; off >= 1; off >>= 1)
                ls += __shfl_xor(ls, off, 64);
            l_run[r] = l_run[r] * alpha[r] + ls;
        }

        // ---- rescale O, write P (hi/lo) to wave-private LDS ----
        #pragma unroll
        for (int nf = 0; nf < 4; ++nf) {
            #pragma unroll
            for (int r = 0; r < 4; ++r) {
                o[nf][r] *= alpha[r];
                const int row = quad * 4 + r;
                const int col = nf * 16 + l15;
                float p = sc[nf][r];
                short hi = f2bf(p);
                Ph[w][row * PADB + col] = hi;
                Pl[w][row * PADB + col] = f2bf(p - bf2f(hi));
            }
        }
        // wave-private: in-order DS ops within a wave, no barrier needed

        // ---- O += P V via MFMA (3-term hi/lo) ----
        bf16x8 ph0 = *(const bf16x8*)(&Ph[w][l15 * PADB + quad * 8]);
        bf16x8 ph1 = *(const bf16x8*)(&Ph[w][l15 * PADB + 32 + quad * 8]);
        bf16x8 pl0 = *(const bf16x8*)(&Pl[w][l15 * PADB + quad * 8]);
        bf16x8 pl1 = *(const bf16x8*)(&Pl[w][l15 * PADB + 32 + quad * 8]);
        #pragma unroll
        for (int nf = 0; nf < 4; ++nf) {
            const short* vb_hi = Vhi + (nf * 16 + l15) * PADB + quad * 8;
            const short* vb_lo = Vlo + (nf * 16 + l15) * PADB + quad * 8;
            bf16x8 vh0 = *(const bf16x8*)(vb_hi);
            bf16x8 vh1 = *(const bf16x8*)(vb_hi + 32);
            bf16x8 vl0 = *(const bf16x8*)(vb_lo);
            bf16x8 vl1 = *(const bf16x8*)(vb_lo + 32);
            f32x4 c = o[nf];
            c = __builtin_amdgcn_mfma_f32_16x16x32_bf16(ph0, vh0, c, 0, 0, 0);
            c = __builtin_amdgcn_mfma_f32_16x16x32_bf16(ph1, vh1, c, 0, 0, 0);
            c = __builtin_amdgcn_mfma_f32_16x16x32_bf16(pl0, vh0, c, 0, 0, 0);
            c = __builtin_amdgcn_mfma_f32_16x16x32_bf16(pl1, vh1, c, 0, 0, 0);
            c = __builtin_amdgcn_mfma_f32_16x16x32_bf16(ph0, vl0, c, 0, 0, 0);
            c = __builtin_amdgcn_mfma_f32_16x16x32_bf16(ph1, vl1, c, 0, 0, 0);
            o[nf] = c;
        }
    }

    // ---- epilogue: O/l -> [B,S,D] fp32 ----
    const int b = bh >> 4, hh = bh & 15;
    #pragma unroll
    for (int nf = 0; nf < 4; ++nf) {
        #pragma unroll
        for (int r = 0; r < 4; ++r) {
            const int q = q0 + quad * 4 + r;
            const int d = nf * 16 + l15;
            Og[(((size_t)(b * SEQ + q) * NHEADS) + hh) * DHEAD + d] = o[nf][r] / l_run[r];
        }
    }
}

// ---------------- launch ----------------
extern "C" void kernel_launch(void* const* d_in, const int* in_sizes, int n_in,
                              void* d_out, int out_size, void* d_ws, size_t ws_size,
                              hipStream_t stream) {
    const float* x  = (const float*)d_in[0];
    // d_in[1] = pH : softmax shift-invariant, ignored
    const float* Wq = (const float*)d_in[2];
    const float* bq = (const float*)d_in[3];
    const float* Wk = (const float*)d_in[4];
    const float* bk = (const float*)d_in[5];
    const float* Wv = (const float*)d_in[6];
    const float* bv = (const float*)d_in[7];
    const float* Wo = (const float*)d_in[8];
    const float* bo = (const float*)d_in[9];
    float* out = (float*)d_out;

    float* ws = (float*)d_ws;
    const size_t SZ = (size_t)MROWS * DMODEL;
    float* q  = ws;
    float* k  = ws + SZ;
    float* v  = ws + 2 * SZ;
    float* ao = ws + 3 * SZ;

    dim3 gemm_grid(DMODEL / TILE, MROWS / TILE);
    dim3 blk(256);

    // fold 1/sqrt(dh) * log2(e) into q so softmax can run base-2
    const float qscale = 0.125f * 1.44269504088896f;
    hipLaunchKernelGGL(gemm_kernel, gemm_grid, blk, 0, stream,
                       x, Wq, bq, q, MROWS, DMODEL, DMODEL, 0, qscale);
    hipLaunchKernelGGL(gemm_kernel, gemm_grid, blk, 0, stream,
                       x, Wk, bk, k, MROWS, DMODEL, DMODEL, 0, 1.0f);
    hipLaunchKernelGGL(gemm_kernel, gemm_grid, blk, 0, stream,
                       x, Wv, bv, v, MROWS, DMODEL, DMODEL, 0, 1.0f);

    dim3 attn_grid(BATCH * NHEADS * (SEQ / 64));  // 1024 blocks
    hipLaunchKernelGGL(attn_mfma, attn_grid, blk, 0, stream, q, k, v, ao);

    hipLaunchKernelGGL(gemm_kernel, gemm_grid, blk, 0, stream,
                       ao, Wo, bo, out, MROWS, DMODEL, DMODEL, 1, 1.0f);
}

// Round 3
// 563.479 us; speedup vs baseline: 3.2040x; 1.6818x over previous
//
#include <hip/hip_runtime.h>
#include <hip/hip_bf16.h>
#include <math.h>

// Problem constants
#define BATCH 2
#define SEQ   2048
#define DMODEL 1024
#define NHEADS 16
#define DHEAD 64
#define MROWS (BATCH*SEQ)   // 4096

typedef __attribute__((ext_vector_type(8))) short bf16x8;
typedef __attribute__((ext_vector_type(4))) short bf16x4;
typedef __attribute__((ext_vector_type(4))) float f32x4;

__device__ __forceinline__ short f2bf(float f) {   // RNE float->bf16
    union { float f; unsigned u; } c; c.f = f;
    unsigned r = (c.u + 0x7fffu + ((c.u >> 16) & 1u)) >> 16;
    return (short)r;
}
__device__ __forceinline__ float bf2f(short h) {
    union { unsigned u; float f; } c; c.u = ((unsigned)(unsigned short)h) << 16;
    return c.f;
}

__device__ __forceinline__ void async_ld16(const void* g, void* l) {
    __builtin_amdgcn_global_load_lds(
        (const __attribute__((address_space(1))) unsigned*)g,
        (__attribute__((address_space(3))) unsigned*)l, 16, 0, 0);
}

// ---------------- convert: fp32 -> bf16 hi/lo (8 elems/thread) ----------------
__global__ __launch_bounds__(256) void convert_hl(
    const float* __restrict__ in, short* __restrict__ hi, short* __restrict__ lo, int n8)
{
    const int i = blockIdx.x * 256 + threadIdx.x;
    if (i >= n8) return;
    const float4* p = (const float4*)in + (size_t)i * 2;
    float4 a = p[0], b = p[1];
    float v[8] = {a.x, a.y, a.z, a.w, b.x, b.y, b.z, b.w};
    bf16x8 H, L;
    #pragma unroll
    for (int j = 0; j < 8; ++j) {
        short h = f2bf(v[j]);
        H[j] = h;
        L[j] = f2bf(v[j] - bf2f(h));
    }
    *((bf16x8*)hi + i) = H;
    *((bf16x8*)lo + i) = L;
}

// ---------------- transpose+convert: W[1024][1024] fp32 -> Wt[N][K] bf16 hi/lo ----------------
__global__ __launch_bounds__(256) void transpose_w(
    const float* __restrict__ W, short* __restrict__ Whi, short* __restrict__ Wlo)
{
    __shared__ float T[64][65];
    const int tid = threadIdx.x;
    const int n0 = blockIdx.x * 64, k0 = blockIdx.y * 64;
    #pragma unroll
    for (int i = 0; i < 16; ++i) {
        const int idx = tid + i * 256;
        const int r = idx >> 6, c = idx & 63;
        T[r][c] = W[(size_t)(k0 + r) * DMODEL + n0 + c];
    }
    __syncthreads();
    #pragma unroll
    for (int i = 0; i < 16; ++i) {
        const int idx = tid + i * 256;
        const int r = idx >> 6, c = idx & 63;   // out row n0+r, col k0+c
        const float v = T[c][r];
        const short h = f2bf(v);
        Whi[(size_t)(n0 + r) * DMODEL + k0 + c] = h;
        Wlo[(size_t)(n0 + r) * DMODEL + k0 + c] = f2bf(v - bf2f(h));
    }
}

// ---------------- MFMA GEMM: C = A[M,K] * Bt[N,K]^T, bf16 hi/lo 3-term ----------------
// 128x128 tile, BK=32, 4 waves (2x2), global_load_lds staging, m97 structure.
// mode 0: scatter to q/k/v [B,H,S,dh] with per-matrix bias + qscale on q
// mode 1: row-major [M,1024] write with bias b0
#define GBK 32

__global__ __launch_bounds__(256) void mfma_gemm(
    const short* __restrict__ Ahi, const short* __restrict__ Alo,
    const short* __restrict__ Bthi, const short* __restrict__ Btlo,
    const float* __restrict__ b0, const float* __restrict__ b1, const float* __restrict__ b2,
    float* __restrict__ oq, float* __restrict__ ok, float* __restrict__ ov,
    int N, int mode, float qscale)
{
    __shared__ short Ah[128 * GBK], Al[128 * GBK], Bh[128 * GBK], Bl[128 * GBK]; // 8 KB each

    const int tid  = threadIdx.x;
    const int lane = tid & 63;
    const int w    = tid >> 6;
    const int quad = lane >> 4;
    const int l15  = lane & 15;
    const int wr   = w >> 1, wc = w & 1;
    const int m0   = blockIdx.y * 128;
    const int n0   = blockIdx.x * 128;
    const int K    = DMODEL;

    f32x4 acc[4][4] = {};

    // per-wave staging assignment: 2 calls per buffer per K-step
    const int cb0 = w * 2 * 64;          // first chunk base for this wave
    const int ch0 = cb0 + lane;          // chunk index for call 0
    const int ch1 = cb0 + 64 + lane;     // chunk index for call 1
    const int r0 = ch0 >> 2, q0c = ch0 & 3;
    const int r1 = ch1 >> 2, q1c = ch1 & 3;

    for (int k0 = 0; k0 < K; k0 += GBK) {
        __syncthreads();   // protect LDS from previous iteration's readers
        {
            const short* gA0h = Ahi + (size_t)(m0 + r0) * K + k0 + q0c * 8;
            const short* gA1h = Ahi + (size_t)(m0 + r1) * K + k0 + q1c * 8;
            const short* gA0l = Alo + (size_t)(m0 + r0) * K + k0 + q0c * 8;
            const short* gA1l = Alo + (size_t)(m0 + r1) * K + k0 + q1c * 8;
            const short* gB0h = Bthi + (size_t)(n0 + r0) * K + k0 + q0c * 8;
            const short* gB1h = Bthi + (size_t)(n0 + r1) * K + k0 + q1c * 8;
            const short* gB0l = Btlo + (size_t)(n0 + r0) * K + k0 + q0c * 8;
            const short* gB1l = Btlo + (size_t)(n0 + r1) * K + k0 + q1c * 8;
            async_ld16(gA0h, Ah + cb0 * 8);
            async_ld16(gA1h, Ah + (cb0 + 64) * 8);
            async_ld16(gA0l, Al + cb0 * 8);
            async_ld16(gA1l, Al + (cb0 + 64) * 8);
            async_ld16(gB0h, Bh + cb0 * 8);
            async_ld16(gB1h, Bh + (cb0 + 64) * 8);
            async_ld16(gB0l, Bl + cb0 * 8);
            async_ld16(gB1l, Bl + (cb0 + 64) * 8);
        }
        __syncthreads();   // drain (compiler emits vmcnt(0) before barrier)

        bf16x8 afh[4], afl[4], bfh[4], bfl[4];
        #pragma unroll
        for (int mi = 0; mi < 4; ++mi) {
            const int row = wr * 64 + mi * 16 + l15;
            afh[mi] = *(const bf16x8*)(Ah + row * GBK + quad * 8);
            afl[mi] = *(const bf16x8*)(Al + row * GBK + quad * 8);
        }
        #pragma unroll
        for (int ni = 0; ni < 4; ++ni) {
            const int row = wc * 64 + ni * 16 + l15;
            bfh[ni] = *(const bf16x8*)(Bh + row * GBK + quad * 8);
            bfl[ni] = *(const bf16x8*)(Bl + row * GBK + quad * 8);
        }
        #pragma unroll
        for (int mi = 0; mi < 4; ++mi)
            #pragma unroll
            for (int ni = 0; ni < 4; ++ni) {
                f32x4 c = acc[mi][ni];
                c = __builtin_amdgcn_mfma_f32_16x16x32_bf16(afh[mi], bfh[ni], c, 0, 0, 0);
                c = __builtin_amdgcn_mfma_f32_16x16x32_bf16(afl[mi], bfh[ni], c, 0, 0, 0);
                c = __builtin_amdgcn_mfma_f32_16x16x32_bf16(afh[mi], bfl[ni], c, 0, 0, 0);
                acc[mi][ni] = c;
            }
    }

    // ---- epilogue ----
    const int nbase = n0 + wc * 64;
    if (mode == 0) {
        const int which = nbase >> 10;                      // uniform per wave
        const float* bias = (which == 0) ? b0 : (which == 1) ? b1 : b2;
        float* outp = (which == 0) ? oq : (which == 1) ? ok : ov;
        const float scl = (which == 0) ? qscale : 1.0f;
        #pragma unroll
        for (int mi = 0; mi < 4; ++mi)
            #pragma unroll
            for (int ni = 0; ni < 4; ++ni)
                #pragma unroll
                for (int r = 0; r < 4; ++r) {
                    const int m = m0 + wr * 64 + mi * 16 + quad * 4 + r;
                    const int nn = (nbase + ni * 16 + l15) & 1023;
                    const int b = m >> 11, s = m & (SEQ - 1);
                    const int h = nn >> 6, d = nn & 63;
                    outp[((size_t)(b * NHEADS + h) * SEQ + s) * DHEAD + d] =
                        (acc[mi][ni][r] + bias[nn]) * scl;
                }
    } else {
        #pragma unroll
        for (int mi = 0; mi < 4; ++mi)
            #pragma unroll
            for (int ni = 0; ni < 4; ++ni)
                #pragma unroll
                for (int r = 0; r < 4; ++r) {
                    const int m = m0 + wr * 64 + mi * 16 + quad * 4 + r;
                    const int nn = nbase + ni * 16 + l15;
                    oq[(size_t)m * DMODEL + nn] = acc[mi][ni][r] + b0[nn];
                }
    }
}

// ---------------- MFMA flash attention (unchanged from R2) ----------------
#define PADB 72

__global__ __launch_bounds__(256) void attn_mfma(
    const float* __restrict__ Qg, const float* __restrict__ Kg,
    const float* __restrict__ Vg, float* __restrict__ Og)
{
    __shared__ short Khi[64 * PADB], Klo[64 * PADB];
    __shared__ short Vhi[64 * PADB], Vlo[64 * PADB];
    __shared__ short Ph[4][16 * PADB], Pl[4][16 * PADB];

    const int tid  = threadIdx.x;
    const int lane = tid & 63;
    const int w    = tid >> 6;
    const int quad = lane >> 4;
    const int l15  = lane & 15;

    const int qtile = blockIdx.x & 31;
    const int bh    = blockIdx.x >> 5;
    const int q0    = qtile * 64 + w * 16;
    const size_t base = (size_t)bh * SEQ * DHEAD;

    bf16x8 qhi[2], qlo[2];
    {
        const float* qrow = Qg + base + (size_t)(q0 + l15) * DHEAD;
        #pragma unroll
        for (int h = 0; h < 2; ++h) {
            const int d0 = h * 32 + quad * 8;
            float4 v0 = *(const float4*)(qrow + d0);
            float4 v1 = *(const float4*)(qrow + d0 + 4);
            float vv[8] = {v0.x, v0.y, v0.z, v0.w, v1.x, v1.y, v1.z, v1.w};
            #pragma unroll
            for (int j = 0; j < 8; ++j) {
                short hi = f2bf(vv[j]);
                qhi[h][j] = hi;
                qlo[h][j] = f2bf(vv[j] - bf2f(hi));
            }
        }
    }

    f32x4 o[4] = {};
    float m_run[4], l_run[4];
    #pragma unroll
    for (int r = 0; r < 4; ++r) { m_run[r] = -INFINITY; l_run[r] = 0.f; }

    for (int kb = 0; kb < SEQ; kb += 64) {
        __syncthreads();
        #pragma unroll
        for (int i = 0; i < 4; ++i) {
            const int r = (tid >> 4) + i * 16;
            const int c = (tid & 15) * 4;
            float4 kv = *(const float4*)(Kg + base + (size_t)(kb + r) * DHEAD + c);
            float kf[4] = {kv.x, kv.y, kv.z, kv.w};
            bf16x4 kh, kl;
            #pragma unroll
            for (int j = 0; j < 4; ++j) {
                short hi = f2bf(kf[j]); kh[j] = hi; kl[j] = f2bf(kf[j] - bf2f(hi));
            }
            *(bf16x4*)(Khi + r * PADB + c) = kh;
            *(bf16x4*)(Klo + r * PADB + c) = kl;

            float4 vv = *(const float4*)(Vg + base + (size_t)(kb + r) * DHEAD + c);
            float vf[4] = {vv.x, vv.y, vv.z, vv.w};
            #pragma unroll
            for (int j = 0; j < 4; ++j) {
                short hi = f2bf(vf[j]);
                Vhi[(c + j) * PADB + r] = hi;
                Vlo[(c + j) * PADB + r] = f2bf(vf[j] - bf2f(hi));
            }
        }
        __syncthreads();

        f32x4 sc[4] = {};
        #pragma unroll
        for (int nf = 0; nf < 4; ++nf) {
            const short* kb_hi = Khi + (nf * 16 + l15) * PADB + quad * 8;
            const short* kb_lo = Klo + (nf * 16 + l15) * PADB + quad * 8;
            bf16x8 kh0 = *(const bf16x8*)(kb_hi);
            bf16x8 kh1 = *(const bf16x8*)(kb_hi + 32);
            bf16x8 kl0 = *(const bf16x8*)(kb_lo);
            bf16x8 kl1 = *(const bf16x8*)(kb_lo + 32);
            f32x4 c = sc[nf];
            c = __builtin_amdgcn_mfma_f32_16x16x32_bf16(qhi[0], kh0, c, 0, 0, 0);
            c = __builtin_amdgcn_mfma_f32_16x16x32_bf16(qhi[1], kh1, c, 0, 0, 0);
            c = __builtin_amdgcn_mfma_f32_16x16x32_bf16(qlo[0], kh0, c, 0, 0, 0);
            c = __builtin_amdgcn_mfma_f32_16x16x32_bf16(qlo[1], kh1, c, 0, 0, 0);
            c = __builtin_amdgcn_mfma_f32_16x16x32_bf16(qhi[0], kl0, c, 0, 0, 0);
            c = __builtin_amdgcn_mfma_f32_16x16x32_bf16(qhi[1], kl1, c, 0, 0, 0);
            sc[nf] = c;
        }

        float alpha[4];
        #pragma unroll
        for (int r = 0; r < 4; ++r) {
            float mb = fmaxf(fmaxf(sc[0][r], sc[1][r]), fmaxf(sc[2][r], sc[3][r]));
            #pragma unroll
            for (int off = 8; off >= 1; off >>= 1)
                mb = fmaxf(mb, __shfl_xor(mb, off, 64));
            const float m_new = fmaxf(m_run[r], mb);
            alpha[r] = exp2f(m_run[r] - m_new);
            m_run[r] = m_new;
            float ls = 0.f;
            #pragma unroll
            for (int nf = 0; nf < 4; ++nf) {
                float p = exp2f(sc[nf][r] - m_new);
                sc[nf][r] = p;
                ls += p;
            }
            #pragma unroll
            for (int off = 8; off >= 1; off >>= 1)
                ls += __shfl_xor(ls, off, 64);
            l_run[r] = l_run[r] * alpha[r] + ls;
        }

        #pragma unroll
        for (int nf = 0; nf < 4; ++nf) {
            #pragma unroll
            for (int r = 0; r < 4; ++r) {
                o[nf][r] *= alpha[r];
                const int row = quad * 4 + r;
                const int col = nf * 16 + l15;
                float p = sc[nf][r];
                short hi = f2bf(p);
                Ph[w][row * PADB + col] = hi;
                Pl[w][row * PADB + col] = f2bf(p - bf2f(hi));
            }
        }

        bf16x8 ph0 = *(const bf16x8*)(&Ph[w][l15 * PADB + quad * 8]);
        bf16x8 ph1 = *(const bf16x8*)(&Ph[w][l15 * PADB + 32 + quad * 8]);
        bf16x8 pl0 = *(const bf16x8*)(&Pl[w][l15 * PADB + quad * 8]);
        bf16x8 pl1 = *(const bf16x8*)(&Pl[w][l15 * PADB + 32 + quad * 8]);
        #pragma unroll
        for (int nf = 0; nf < 4; ++nf) {
            const short* vb_hi = Vhi + (nf * 16 + l15) * PADB + quad * 8;
            const short* vb_lo = Vlo + (nf * 16 + l15) * PADB + quad * 8;
            bf16x8 vh0 = *(const bf16x8*)(vb_hi);
            bf16x8 vh1 = *(const bf16x8*)(vb_hi + 32);
            bf16x8 vl0 = *(const bf16x8*)(vb_lo);
            bf16x8 vl1 = *(const bf16x8*)(vb_lo + 32);
            f32x4 c = o[nf];
            c = __builtin_amdgcn_mfma_f32_16x16x32_bf16(ph0, vh0, c, 0, 0, 0);
            c = __builtin_amdgcn_mfma_f32_16x16x32_bf16(ph1, vh1, c, 0, 0, 0);
            c = __builtin_amdgcn_mfma_f32_16x16x32_bf16(pl0, vh0, c, 0, 0, 0);
            c = __builtin_amdgcn_mfma_f32_16x16x32_bf16(pl1, vh1, c, 0, 0, 0);
            c = __builtin_amdgcn_mfma_f32_16x16x32_bf16(ph0, vl0, c, 0, 0, 0);
            c = __builtin_amdgcn_mfma_f32_16x16x32_bf16(ph1, vl1, c, 0, 0, 0);
            o[nf] = c;
        }
    }

    const int b = bh >> 4, hh = bh & 15;
    #pragma unroll
    for (int nf = 0; nf < 4; ++nf) {
        #pragma unroll
        for (int r = 0; r < 4; ++r) {
            const int q = q0 + quad * 4 + r;
            const int d = nf * 16 + l15;
            Og[(((size_t)(b * SEQ + q) * NHEADS) + hh) * DHEAD + d] = o[nf][r] / l_run[r];
        }
    }
}

// ---------------- launch ----------------
extern "C" void kernel_launch(void* const* d_in, const int* in_sizes, int n_in,
                              void* d_out, int out_size, void* d_ws, size_t ws_size,
                              hipStream_t stream) {
    const float* x  = (const float*)d_in[0];
    // d_in[1] = pH : softmax shift-invariant, ignored
    const float* Wq = (const float*)d_in[2];
    const float* bq = (const float*)d_in[3];
    const float* Wk = (const float*)d_in[4];
    const float* bk = (const float*)d_in[5];
    const float* Wv = (const float*)d_in[6];
    const float* bv = (const float*)d_in[7];
    const float* Wo = (const float*)d_in[8];
    const float* bo = (const float*)d_in[9];
    float* out = (float*)d_out;

    char* ws = (char*)d_ws;
    const size_t MB = 1024 * 1024;
    float* q  = (float*)(ws + 0 * MB);      // 16 MB
    float* k  = (float*)(ws + 16 * MB);     // 16 MB
    float* v  = (float*)(ws + 32 * MB);     // 16 MB
    float* ao = (float*)(ws + 48 * MB);     // 16 MB
    short* xhi = (short*)(ws + 64 * MB);    // 8 MB (reused for ao)
    short* xlo = (short*)(ws + 72 * MB);    // 8 MB
    short* wqkv_hi = (short*)(ws + 80 * MB); // 6 MB  [3072][1024]
    short* wqkv_lo = (short*)(ws + 86 * MB); // 6 MB
    short* wto_hi  = (short*)(ws + 92 * MB); // 2 MB  [1024][1024]
    short* wto_lo  = (short*)(ws + 94 * MB); // 2 MB

    dim3 blk(256);
    const int n8 = MROWS * DMODEL / 8;       // 524288

    // 1) convert x -> bf16 hi/lo
    hipLaunchKernelGGL(convert_hl, dim3(n8 / 256), blk, 0, stream, x, xhi, xlo, n8);

    // 2) transpose+convert weights (Wt[N][K])
    dim3 tgrid(16, 16);
    hipLaunchKernelGGL(transpose_w, tgrid, blk, 0, stream, Wq, wqkv_hi, wqkv_lo);
    hipLaunchKernelGGL(transpose_w, tgrid, blk, 0, stream, Wk, wqkv_hi + 1024 * 1024, wqkv_lo + 1024 * 1024);
    hipLaunchKernelGGL(transpose_w, tgrid, blk, 0, stream, Wv, wqkv_hi + 2 * 1024 * 1024, wqkv_lo + 2 * 1024 * 1024);
    hipLaunchKernelGGL(transpose_w, tgrid, blk, 0, stream, Wo, wto_hi, wto_lo);

    // 3) fused QKV GEMM (N=3072), scatter epilogue, q-scale folded (base-2 softmax)
    const float qscale = 0.125f * 1.44269504088896f;
    hipLaunchKernelGGL(mfma_gemm, dim3(3072 / 128, MROWS / 128), blk, 0, stream,
                       xhi, xlo, wqkv_hi, wqkv_lo, bq, bk, bv, q, k, v, 3072, 0, qscale);

    // 4) attention
    hipLaunchKernelGGL(attn_mfma, dim3(BATCH * NHEADS * (SEQ / 64)), blk, 0, stream, q, k, v, ao);

    // 5) convert ao -> bf16 hi/lo (reuse x buffers)
    hipLaunchKernelGGL(convert_hl, dim3(n8 / 256), blk, 0, stream, ao, xhi, xlo, n8);

    // 6) output projection GEMM (N=1024), row-major epilogue
    hipLaunchKernelGGL(mfma_gemm, dim3(1024 / 128, MROWS / 128), blk, 0, stream,
                       xhi, xlo, wto_hi, wto_lo, bo, bo, bo, out, out, out, 1024, 1, 1.0f);
}

// Round 4
// 482.067 us; speedup vs baseline: 3.7451x; 1.1689x over previous
//
#include <hip/hip_runtime.h>
#include <hip/hip_bf16.h>
#include <math.h>

// Problem constants
#define BATCH 2
#define SEQ   2048
#define DMODEL 1024
#define NHEADS 16
#define DHEAD 64
#define MROWS (BATCH*SEQ)   // 4096

typedef __attribute__((ext_vector_type(8))) short bf16x8;
typedef __attribute__((ext_vector_type(4))) short bf16x4;
typedef __attribute__((ext_vector_type(4))) float f32x4;

__device__ __forceinline__ short f2bf(float f) {   // RNE float->bf16
    union { float f; unsigned u; } c; c.f = f;
    unsigned r = (c.u + 0x7fffu + ((c.u >> 16) & 1u)) >> 16;
    return (short)r;
}
__device__ __forceinline__ float bf2f(short h) {
    union { unsigned u; float f; } c; c.u = ((unsigned)(unsigned short)h) << 16;
    return c.f;
}

__device__ __forceinline__ void async_ld16(const void* g, void* l) {
    __builtin_amdgcn_global_load_lds(
        (const __attribute__((address_space(1))) unsigned*)g,
        (__attribute__((address_space(3))) unsigned*)l, 16, 0, 0);
}

// ---------------- convert: fp32 -> bf16 hi/lo (8 elems/thread) ----------------
__global__ __launch_bounds__(256) void convert_hl(
    const float* __restrict__ in, short* __restrict__ hi, short* __restrict__ lo, int n8)
{
    const int i = blockIdx.x * 256 + threadIdx.x;
    if (i >= n8) return;
    const float4* p = (const float4*)in + (size_t)i * 2;
    float4 a = p[0], b = p[1];
    float v[8] = {a.x, a.y, a.z, a.w, b.x, b.y, b.z, b.w};
    bf16x8 H, L;
    #pragma unroll
    for (int j = 0; j < 8; ++j) {
        short h = f2bf(v[j]);
        H[j] = h;
        L[j] = f2bf(v[j] - bf2f(h));
    }
    *((bf16x8*)hi + i) = H;
    *((bf16x8*)lo + i) = L;
}

// ---------------- transpose+convert: W[1024][1024] fp32 -> Wt[N][K] bf16 hi/lo ----------------
__global__ __launch_bounds__(256) void transpose_w(
    const float* __restrict__ W, short* __restrict__ Whi, short* __restrict__ Wlo)
{
    __shared__ float T[64][65];
    const int tid = threadIdx.x;
    const int n0 = blockIdx.x * 64, k0 = blockIdx.y * 64;
    #pragma unroll
    for (int i = 0; i < 16; ++i) {
        const int idx = tid + i * 256;
        const int r = idx >> 6, c = idx & 63;
        T[r][c] = W[(size_t)(k0 + r) * DMODEL + n0 + c];
    }
    __syncthreads();
    #pragma unroll
    for (int i = 0; i < 16; ++i) {
        const int idx = tid + i * 256;
        const int r = idx >> 6, c = idx & 63;
        const float v = T[c][r];
        const short h = f2bf(v);
        Whi[(size_t)(n0 + r) * DMODEL + k0 + c] = h;
        Wlo[(size_t)(n0 + r) * DMODEL + k0 + c] = f2bf(v - bf2f(h));
    }
}

// ---------------- MFMA GEMM: C = A[M,K] * Bt[N,K]^T, bf16 hi/lo 3-term ----------------
// mode 0: emit q/k bf16 hi/lo [B,H,S,64], v bf16 hi/lo transposed [B,H,64,S]
// mode 1: row-major fp32 [M,1024] with bias b0
#define GBK 32

__global__ __launch_bounds__(256) void mfma_gemm(
    const short* __restrict__ Ahi, const short* __restrict__ Alo,
    const short* __restrict__ Bthi, const short* __restrict__ Btlo,
    const float* __restrict__ b0, const float* __restrict__ b1, const float* __restrict__ b2,
    short* __restrict__ oqh, short* __restrict__ oql,
    short* __restrict__ okh, short* __restrict__ okl,
    short* __restrict__ ovh, short* __restrict__ ovl,
    float* __restrict__ outf, int mode, float qscale)
{
    __shared__ short Ah[128 * GBK], Al[128 * GBK], Bh[128 * GBK], Bl[128 * GBK];

    const int tid  = threadIdx.x;
    const int lane = tid & 63;
    const int w    = tid >> 6;
    const int quad = lane >> 4;
    const int l15  = lane & 15;
    const int wr   = w >> 1, wc = w & 1;
    const int m0   = blockIdx.y * 128;
    const int n0   = blockIdx.x * 128;
    const int K    = DMODEL;

    f32x4 acc[4][4] = {};

    const int cb0 = w * 2 * 64;
    const int ch0 = cb0 + lane;
    const int ch1 = cb0 + 64 + lane;
    const int r0 = ch0 >> 2, q0c = ch0 & 3;
    const int r1 = ch1 >> 2, q1c = ch1 & 3;

    for (int k0 = 0; k0 < K; k0 += GBK) {
        __syncthreads();
        {
            async_ld16(Ahi + (size_t)(m0 + r0) * K + k0 + q0c * 8, Ah + cb0 * 8);
            async_ld16(Ahi + (size_t)(m0 + r1) * K + k0 + q1c * 8, Ah + (cb0 + 64) * 8);
            async_ld16(Alo + (size_t)(m0 + r0) * K + k0 + q0c * 8, Al + cb0 * 8);
            async_ld16(Alo + (size_t)(m0 + r1) * K + k0 + q1c * 8, Al + (cb0 + 64) * 8);
            async_ld16(Bthi + (size_t)(n0 + r0) * K + k0 + q0c * 8, Bh + cb0 * 8);
            async_ld16(Bthi + (size_t)(n0 + r1) * K + k0 + q1c * 8, Bh + (cb0 + 64) * 8);
            async_ld16(Btlo + (size_t)(n0 + r0) * K + k0 + q0c * 8, Bl + cb0 * 8);
            async_ld16(Btlo + (size_t)(n0 + r1) * K + k0 + q1c * 8, Bl + (cb0 + 64) * 8);
        }
        __syncthreads();

        bf16x8 afh[4], afl[4], bfh[4], bfl[4];
        #pragma unroll
        for (int mi = 0; mi < 4; ++mi) {
            const int row = wr * 64 + mi * 16 + l15;
            afh[mi] = *(const bf16x8*)(Ah + row * GBK + quad * 8);
            afl[mi] = *(const bf16x8*)(Al + row * GBK + quad * 8);
        }
        #pragma unroll
        for (int ni = 0; ni < 4; ++ni) {
            const int row = wc * 64 + ni * 16 + l15;
            bfh[ni] = *(const bf16x8*)(Bh + row * GBK + quad * 8);
            bfl[ni] = *(const bf16x8*)(Bl + row * GBK + quad * 8);
        }
        #pragma unroll
        for (int mi = 0; mi < 4; ++mi)
            #pragma unroll
            for (int ni = 0; ni < 4; ++ni) {
                f32x4 c = acc[mi][ni];
                c = __builtin_amdgcn_mfma_f32_16x16x32_bf16(afh[mi], bfh[ni], c, 0, 0, 0);
                c = __builtin_amdgcn_mfma_f32_16x16x32_bf16(afl[mi], bfh[ni], c, 0, 0, 0);
                c = __builtin_amdgcn_mfma_f32_16x16x32_bf16(afh[mi], bfl[ni], c, 0, 0, 0);
                acc[mi][ni] = c;
            }
    }

    const int nbase = n0 + wc * 64;
    if (mode == 1) {
        #pragma unroll
        for (int mi = 0; mi < 4; ++mi)
            #pragma unroll
            for (int ni = 0; ni < 4; ++ni)
                #pragma unroll
                for (int r = 0; r < 4; ++r) {
                    const int m = m0 + wr * 64 + mi * 16 + quad * 4 + r;
                    const int nn = nbase + ni * 16 + l15;
                    outf[(size_t)m * DMODEL + nn] = acc[mi][ni][r] + b0[nn];
                }
    } else {
        const int which = nbase >> 10;               // 0=q, 1=k, 2=v (wave-uniform)
        if (which < 2) {
            const float* bias = which ? b1 : b0;
            short* sh = which ? okh : oqh;
            short* sl = which ? okl : oql;
            const float scl = which ? 1.0f : qscale;
            #pragma unroll
            for (int mi = 0; mi < 4; ++mi)
                #pragma unroll
                for (int ni = 0; ni < 4; ++ni)
                    #pragma unroll
                    for (int r = 0; r < 4; ++r) {
                        const int m = m0 + wr * 64 + mi * 16 + quad * 4 + r;
                        const int nn = (nbase + ni * 16 + l15) & 1023;
                        const int b = m >> 11, s = m & (SEQ - 1);
                        const int h = nn >> 6, d = nn & 63;
                        const float val = (acc[mi][ni][r] + bias[nn]) * scl;
                        const short hi = f2bf(val);
                        const size_t idx = ((size_t)(b * NHEADS + h) * SEQ + s) * DHEAD + d;
                        sh[idx] = hi;
                        sl[idx] = f2bf(val - bf2f(hi));
                    }
        } else {
            // V: write transposed [B,H,64,S], 4 consecutive s per 8B store
            #pragma unroll
            for (int mi = 0; mi < 4; ++mi) {
                const int mb = m0 + wr * 64 + mi * 16 + quad * 4;
                const int b = mb >> 11, s0 = mb & (SEQ - 1);
                #pragma unroll
                for (int ni = 0; ni < 4; ++ni) {
                    const int nn = (nbase + ni * 16 + l15) & 1023;
                    const int h = nn >> 6, d = nn & 63;
                    bf16x4 H, L;
                    #pragma unroll
                    for (int r = 0; r < 4; ++r) {
                        const float val = acc[mi][ni][r] + b2[nn];
                        const short hi = f2bf(val);
                        H[r] = hi;
                        L[r] = f2bf(val - bf2f(hi));
                    }
                    const size_t idx = ((size_t)(b * NHEADS + h) * DHEAD + d) * SEQ + s0;
                    *(bf16x4*)(ovh + idx) = H;
                    *(bf16x4*)(ovl + idx) = L;
                }
            }
        }
    }
}

// ---------------- MFMA flash attention v2 ----------------
// All-bf16 inputs (hi/lo), K [B,H,S,64], Vt [B,H,64,S]. global_load_lds staging
// with XOR-8 chunk swizzle (row stride 128B = 8 chunks of 16B; pos ^= row&7).
// Output written as bf16 hi/lo in GEMM-A layout [M=b*S+q][h*64+d].
#define PP 72   // P tile row pad (shorts)

__global__ __launch_bounds__(256) void attn_mfma(
    const short* __restrict__ Qh_g, const short* __restrict__ Ql_g,
    const short* __restrict__ Kh_g, const short* __restrict__ Kl_g,
    const short* __restrict__ Vth_g, const short* __restrict__ Vtl_g,
    short* __restrict__ Oh_g, short* __restrict__ Ol_g)
{
    __shared__ short Ksh[4096], Ksl[4096];   // [key][d] 64x64, swizzled
    __shared__ short Vsh[4096], Vsl[4096];   // [d][s]  64x64, swizzled
    __shared__ short Ph[4][16 * PP], Pl[4][16 * PP];

    const int tid  = threadIdx.x;
    const int lane = tid & 63;
    const int w    = tid >> 6;
    const int quad = lane >> 4;
    const int l15  = lane & 15;

    const int qtile = blockIdx.x & 31;
    const int bh    = blockIdx.x >> 5;
    const int q0    = qtile * 64 + w * 16;
    const size_t kvb = (size_t)bh * SEQ * DHEAD;   // element offset

    // ---- Q fragments: direct bf16 hi/lo global loads ----
    bf16x8 qhi[2], qlo[2];
    {
        const size_t qr = kvb + (size_t)(q0 + l15) * DHEAD;
        #pragma unroll
        for (int h = 0; h < 2; ++h) {
            qhi[h] = *(const bf16x8*)(Qh_g + qr + h * 32 + quad * 8);
            qlo[h] = *(const bf16x8*)(Ql_g + qr + h * 32 + quad * 8);
        }
    }

    // wave staging assignment: wave w owns one buffer
    short* dst = (w == 0) ? Ksh : (w == 1) ? Ksl : (w == 2) ? Vsh : Vsl;

    f32x4 o[4] = {};
    float m_run[4], l_run[4];
    #pragma unroll
    for (int r = 0; r < 4; ++r) { m_run[r] = -INFINITY; l_run[r] = 0.f; }

    for (int kb = 0; kb < SEQ; kb += 64) {
        __syncthreads();
        {
            const short* src = (w == 0) ? (Kh_g + kvb + (size_t)kb * DHEAD)
                             : (w == 1) ? (Kl_g + kvb + (size_t)kb * DHEAD)
                             : (w == 2) ? (Vth_g + kvb + kb)
                                        : (Vtl_g + kvb + kb);
            const bool isv = (w >= 2);
            #pragma unroll
            for (int j = 0; j < 8; ++j) {
                const int c = j * 64 + lane;
                const int row = c >> 3, pos = c & 7;
                const int gq = pos ^ (row & 7);
                const short* g = src + (isv ? ((size_t)row * SEQ + gq * 8)
                                            : ((size_t)row * DHEAD + gq * 8));
                async_ld16(g, dst + j * 512);
            }
        }
        __syncthreads();

        // ---- S = Q K^T ----
        f32x4 sc[4] = {};
        #pragma unroll
        for (int nf = 0; nf < 4; ++nf) {
            const int row = nf * 16 + l15;
            const int sw = row & 7;
            const int o0 = row * 64 + ((quad ^ sw) * 8);          // h=0: p=quad
            const int o1 = row * 64 + (((4 + quad) ^ sw) * 8);    // h=1: p=4+quad
            bf16x8 kh0 = *(const bf16x8*)(Ksh + o0);
            bf16x8 kh1 = *(const bf16x8*)(Ksh + o1);
            bf16x8 kl0 = *(const bf16x8*)(Ksl + o0);
            bf16x8 kl1 = *(const bf16x8*)(Ksl + o1);
            f32x4 c = sc[nf];
            c = __builtin_amdgcn_mfma_f32_16x16x32_bf16(qhi[0], kh0, c, 0, 0, 0);
            c = __builtin_amdgcn_mfma_f32_16x16x32_bf16(qhi[1], kh1, c, 0, 0, 0);
            c = __builtin_amdgcn_mfma_f32_16x16x32_bf16(qlo[0], kh0, c, 0, 0, 0);
            c = __builtin_amdgcn_mfma_f32_16x16x32_bf16(qlo[1], kh1, c, 0, 0, 0);
            c = __builtin_amdgcn_mfma_f32_16x16x32_bf16(qhi[0], kl0, c, 0, 0, 0);
            c = __builtin_amdgcn_mfma_f32_16x16x32_bf16(qhi[1], kl1, c, 0, 0, 0);
            sc[nf] = c;
        }

        // ---- online softmax (base-2) ----
        float alpha[4];
        #pragma unroll
        for (int r = 0; r < 4; ++r) {
            float mb = fmaxf(fmaxf(sc[0][r], sc[1][r]), fmaxf(sc[2][r], sc[3][r]));
            #pragma unroll
            for (int off = 8; off >= 1; off >>= 1)
                mb = fmaxf(mb, __shfl_xor(mb, off, 64));
            const float m_new = fmaxf(m_run[r], mb);
            alpha[r] = exp2f(m_run[r] - m_new);
            m_run[r] = m_new;
            float ls = 0.f;
            #pragma unroll
            for (int nf = 0; nf < 4; ++nf) {
                float p = exp2f(sc[nf][r] - m_new);
                sc[nf][r] = p;
                ls += p;
            }
            #pragma unroll
            for (int off = 8; off >= 1; off >>= 1)
                ls += __shfl_xor(ls, off, 64);
            l_run[r] = l_run[r] * alpha[r] + ls;
        }

        // ---- P -> wave-private LDS (hi/lo) ----
        #pragma unroll
        for (int nf = 0; nf < 4; ++nf) {
            #pragma unroll
            for (int r = 0; r < 4; ++r) {
                o[nf][r] *= alpha[r];
                const int row = quad * 4 + r;
                const int col = nf * 16 + l15;
                const float p = sc[nf][r];
                const short hi = f2bf(p);
                Ph[w][row * PP + col] = hi;
                Pl[w][row * PP + col] = f2bf(p - bf2f(hi));
            }
        }

        bf16x8 ph0 = *(const bf16x8*)(&Ph[w][l15 * PP + quad * 8]);
        bf16x8 ph1 = *(const bf16x8*)(&Ph[w][l15 * PP + 32 + quad * 8]);
        bf16x8 pl0 = *(const bf16x8*)(&Pl[w][l15 * PP + quad * 8]);
        bf16x8 pl1 = *(const bf16x8*)(&Pl[w][l15 * PP + 32 + quad * 8]);

        // ---- O += P V ----
        #pragma unroll
        for (int nf = 0; nf < 4; ++nf) {
            const int row = nf * 16 + l15;
            const int sw = row & 7;
            const int o0 = row * 64 + ((quad ^ sw) * 8);
            const int o1 = row * 64 + (((4 + quad) ^ sw) * 8);
            bf16x8 vh0 = *(const bf16x8*)(Vsh + o0);
            bf16x8 vh1 = *(const bf16x8*)(Vsh + o1);
            bf16x8 vl0 = *(const bf16x8*)(Vsl + o0);
            bf16x8 vl1 = *(const bf16x8*)(Vsl + o1);
            f32x4 c = o[nf];
            c = __builtin_amdgcn_mfma_f32_16x16x32_bf16(ph0, vh0, c, 0, 0, 0);
            c = __builtin_amdgcn_mfma_f32_16x16x32_bf16(ph1, vh1, c, 0, 0, 0);
            c = __builtin_amdgcn_mfma_f32_16x16x32_bf16(pl0, vh0, c, 0, 0, 0);
            c = __builtin_amdgcn_mfma_f32_16x16x32_bf16(pl1, vh1, c, 0, 0, 0);
            c = __builtin_amdgcn_mfma_f32_16x16x32_bf16(ph0, vl0, c, 0, 0, 0);
            c = __builtin_amdgcn_mfma_f32_16x16x32_bf16(ph1, vl1, c, 0, 0, 0);
            o[nf] = c;
        }
    }

    // ---- epilogue: O/l -> bf16 hi/lo GEMM-A layout [b*S+q][h*64+d] ----
    const int b = bh >> 4, hh = bh & 15;
    #pragma unroll
    for (int nf = 0; nf < 4; ++nf) {
        #pragma unroll
        for (int r = 0; r < 4; ++r) {
            const int q = q0 + quad * 4 + r;
            const int d = nf * 16 + l15;
            const float val = o[nf][r] / l_run[r];
            const short hi = f2bf(val);
            const size_t idx = (size_t)(b * SEQ + q) * DMODEL + hh * DHEAD + d;
            Oh_g[idx] = hi;
            Ol_g[idx] = f2bf(val - bf2f(hi));
        }
    }
}

// ---------------- launch ----------------
extern "C" void kernel_launch(void* const* d_in, const int* in_sizes, int n_in,
                              void* d_out, int out_size, void* d_ws, size_t ws_size,
                              hipStream_t stream) {
    const float* x  = (const float*)d_in[0];
    // d_in[1] = pH : softmax shift-invariant, ignored
    const float* Wq = (const float*)d_in[2];
    const float* bq = (const float*)d_in[3];
    const float* Wk = (const float*)d_in[4];
    const float* bk = (const float*)d_in[5];
    const float* Wv = (const float*)d_in[6];
    const float* bv = (const float*)d_in[7];
    const float* Wo = (const float*)d_in[8];
    const float* bo = (const float*)d_in[9];
    float* out = (float*)d_out;

    char* ws = (char*)d_ws;
    const size_t MB = 1024 * 1024;
    short* qh = (short*)(ws + 0 * MB);       // each 8 MB (4M bf16)
    short* ql = (short*)(ws + 8 * MB);
    short* kh = (short*)(ws + 16 * MB);
    short* kl = (short*)(ws + 24 * MB);
    short* vth = (short*)(ws + 32 * MB);
    short* vtl = (short*)(ws + 40 * MB);
    short* aoh = (short*)(ws + 48 * MB);
    short* aol = (short*)(ws + 56 * MB);
    short* xhi = (short*)(ws + 64 * MB);
    short* xlo = (short*)(ws + 72 * MB);
    short* wqkv_hi = (short*)(ws + 80 * MB); // 6 MB [3072][1024]
    short* wqkv_lo = (short*)(ws + 86 * MB);
    short* wto_hi  = (short*)(ws + 92 * MB); // 2 MB
    short* wto_lo  = (short*)(ws + 94 * MB);

    dim3 blk(256);
    const int n8 = MROWS * DMODEL / 8;

    hipLaunchKernelGGL(convert_hl, dim3(n8 / 256), blk, 0, stream, x, xhi, xlo, n8);

    dim3 tgrid(16, 16);
    hipLaunchKernelGGL(transpose_w, tgrid, blk, 0, stream, Wq, wqkv_hi, wqkv_lo);
    hipLaunchKernelGGL(transpose_w, tgrid, blk, 0, stream, Wk, wqkv_hi + 1024 * 1024, wqkv_lo + 1024 * 1024);
    hipLaunchKernelGGL(transpose_w, tgrid, blk, 0, stream, Wv, wqkv_hi + 2 * 1024 * 1024, wqkv_lo + 2 * 1024 * 1024);
    hipLaunchKernelGGL(transpose_w, tgrid, blk, 0, stream, Wo, wto_hi, wto_lo);

    const float qscale = 0.125f * 1.44269504088896f;   // fold 1/sqrt(dh)*log2(e)
    hipLaunchKernelGGL(mfma_gemm, dim3(3072 / 128, MROWS / 128), blk, 0, stream,
                       xhi, xlo, wqkv_hi, wqkv_lo, bq, bk, bv,
                       qh, ql, kh, kl, vth, vtl, (float*)nullptr, 0, qscale);

    hipLaunchKernelGGL(attn_mfma, dim3(BATCH * NHEADS * (SEQ / 64)), blk, 0, stream,
                       qh, ql, kh, kl, vth, vtl, aoh, aol);

    hipLaunchKernelGGL(mfma_gemm, dim3(1024 / 128, MROWS / 128), blk, 0, stream,
                       aoh, aol, wto_hi, wto_lo, bo, bo, bo,
                       (short*)nullptr, (short*)nullptr, (short*)nullptr,
                       (short*)nullptr, (short*)nullptr, (short*)nullptr,
                       out, 1, 1.0f);
}

// Round 5
// 334.155 us; speedup vs baseline: 5.4029x; 1.4426x over previous
//
#include <hip/hip_runtime.h>
#include <hip/hip_bf16.h>
#include <math.h>

// Problem constants
#define BATCH 2
#define SEQ   2048
#define DMODEL 1024
#define NHEADS 16
#define DHEAD 64
#define MROWS (BATCH*SEQ)   // 4096

typedef __attribute__((ext_vector_type(8))) short bf16x8;
typedef __attribute__((ext_vector_type(4))) short bf16x4;
typedef __attribute__((ext_vector_type(4))) float f32x4;

__device__ __forceinline__ short f2bf(float f) {   // RNE float->bf16
    union { float f; unsigned u; } c; c.f = f;
    unsigned r = (c.u + 0x7fffu + ((c.u >> 16) & 1u)) >> 16;
    return (short)r;
}
__device__ __forceinline__ float bf2f(short h) {
    union { unsigned u; float f; } c; c.u = ((unsigned)(unsigned short)h) << 16;
    return c.f;
}

__device__ __forceinline__ void async_ld16(const void* g, void* l) {
    __builtin_amdgcn_global_load_lds(
        (const __attribute__((address_space(1))) unsigned*)g,
        (__attribute__((address_space(3))) unsigned*)l, 16, 0, 0);
}

// ---------------- convert: fp32 -> bf16 hi/lo (8 elems/thread) ----------------
__global__ __launch_bounds__(256) void convert_hl(
    const float* __restrict__ in, short* __restrict__ hi, short* __restrict__ lo, int n8)
{
    const int i = blockIdx.x * 256 + threadIdx.x;
    if (i >= n8) return;
    const float4* p = (const float4*)in + (size_t)i * 2;
    float4 a = p[0], b = p[1];
    float v[8] = {a.x, a.y, a.z, a.w, b.x, b.y, b.z, b.w};
    bf16x8 H, L;
    #pragma unroll
    for (int j = 0; j < 8; ++j) {
        short h = f2bf(v[j]);
        H[j] = h;
        L[j] = f2bf(v[j] - bf2f(h));
    }
    *((bf16x8*)hi + i) = H;
    *((bf16x8*)lo + i) = L;
}

// ---------------- transpose+convert: W[1024][1024] fp32 -> Wt[N][K] bf16 hi/lo ----------------
__global__ __launch_bounds__(256) void transpose_w(
    const float* __restrict__ W, short* __restrict__ Whi, short* __restrict__ Wlo)
{
    __shared__ float T[64][65];
    const int tid = threadIdx.x;
    const int n0 = blockIdx.x * 64, k0 = blockIdx.y * 64;
    #pragma unroll
    for (int i = 0; i < 16; ++i) {
        const int idx = tid + i * 256;
        const int r = idx >> 6, c = idx & 63;
        T[r][c] = W[(size_t)(k0 + r) * DMODEL + n0 + c];
    }
    __syncthreads();
    #pragma unroll
    for (int i = 0; i < 16; ++i) {
        const int idx = tid + i * 256;
        const int r = idx >> 6, c = idx & 63;
        const float v = T[c][r];
        const short h = f2bf(v);
        Whi[(size_t)(n0 + r) * DMODEL + k0 + c] = h;
        Wlo[(size_t)(n0 + r) * DMODEL + k0 + c] = f2bf(v - bf2f(h));
    }
}

// ---------------- MFMA GEMM: C = A[M,K] * Bt[N,K]^T, bf16 hi/lo 3-term ----------------
// mode 0: emit q bf16-hi [B,H,S,64], k bf16 hi/lo [B,H,S,64], v bf16-hi transposed [B,H,64,S]
// mode 1: row-major fp32 [M,1024] with bias b0
#define GBK 32

__global__ __launch_bounds__(256) void mfma_gemm(
    const short* __restrict__ Ahi, const short* __restrict__ Alo,
    const short* __restrict__ Bthi, const short* __restrict__ Btlo,
    const float* __restrict__ b0, const float* __restrict__ b1, const float* __restrict__ b2,
    short* __restrict__ oqh,
    short* __restrict__ okh, short* __restrict__ okl,
    short* __restrict__ ovh,
    float* __restrict__ outf, int mode, float qscale)
{
    __shared__ short Ah[128 * GBK], Al[128 * GBK], Bh[128 * GBK], Bl[128 * GBK];

    const int tid  = threadIdx.x;
    const int lane = tid & 63;
    const int w    = tid >> 6;
    const int quad = lane >> 4;
    const int l15  = lane & 15;
    const int wr   = w >> 1, wc = w & 1;
    const int m0   = blockIdx.y * 128;
    const int n0   = blockIdx.x * 128;
    const int K    = DMODEL;

    f32x4 acc[4][4] = {};

    const int cb0 = w * 2 * 64;
    const int ch0 = cb0 + lane;
    const int ch1 = cb0 + 64 + lane;
    const int r0 = ch0 >> 2, q0c = ch0 & 3;
    const int r1 = ch1 >> 2, q1c = ch1 & 3;

    for (int k0 = 0; k0 < K; k0 += GBK) {
        __syncthreads();
        {
            async_ld16(Ahi + (size_t)(m0 + r0) * K + k0 + q0c * 8, Ah + cb0 * 8);
            async_ld16(Ahi + (size_t)(m0 + r1) * K + k0 + q1c * 8, Ah + (cb0 + 64) * 8);
            async_ld16(Alo + (size_t)(m0 + r0) * K + k0 + q0c * 8, Al + cb0 * 8);
            async_ld16(Alo + (size_t)(m0 + r1) * K + k0 + q1c * 8, Al + (cb0 + 64) * 8);
            async_ld16(Bthi + (size_t)(n0 + r0) * K + k0 + q0c * 8, Bh + cb0 * 8);
            async_ld16(Bthi + (size_t)(n0 + r1) * K + k0 + q1c * 8, Bh + (cb0 + 64) * 8);
            async_ld16(Btlo + (size_t)(n0 + r0) * K + k0 + q0c * 8, Bl + cb0 * 8);
            async_ld16(Btlo + (size_t)(n0 + r1) * K + k0 + q1c * 8, Bl + (cb0 + 64) * 8);
        }
        __syncthreads();

        bf16x8 afh[4], afl[4], bfh[4], bfl[4];
        #pragma unroll
        for (int mi = 0; mi < 4; ++mi) {
            const int row = wr * 64 + mi * 16 + l15;
            afh[mi] = *(const bf16x8*)(Ah + row * GBK + quad * 8);
            afl[mi] = *(const bf16x8*)(Al + row * GBK + quad * 8);
        }
        #pragma unroll
        for (int ni = 0; ni < 4; ++ni) {
            const int row = wc * 64 + ni * 16 + l15;
            bfh[ni] = *(const bf16x8*)(Bh + row * GBK + quad * 8);
            bfl[ni] = *(const bf16x8*)(Bl + row * GBK + quad * 8);
        }
        #pragma unroll
        for (int mi = 0; mi < 4; ++mi)
            #pragma unroll
            for (int ni = 0; ni < 4; ++ni) {
                f32x4 c = acc[mi][ni];
                c = __builtin_amdgcn_mfma_f32_16x16x32_bf16(afh[mi], bfh[ni], c, 0, 0, 0);
                c = __builtin_amdgcn_mfma_f32_16x16x32_bf16(afl[mi], bfh[ni], c, 0, 0, 0);
                c = __builtin_amdgcn_mfma_f32_16x16x32_bf16(afh[mi], bfl[ni], c, 0, 0, 0);
                acc[mi][ni] = c;
            }
    }

    const int nbase = n0 + wc * 64;
    if (mode == 1) {
        #pragma unroll
        for (int mi = 0; mi < 4; ++mi)
            #pragma unroll
            for (int ni = 0; ni < 4; ++ni)
                #pragma unroll
                for (int r = 0; r < 4; ++r) {
                    const int m = m0 + wr * 64 + mi * 16 + quad * 4 + r;
                    const int nn = nbase + ni * 16 + l15;
                    outf[(size_t)m * DMODEL + nn] = acc[mi][ni][r] + b0[nn];
                }
    } else {
        const int which = nbase >> 10;               // 0=q, 1=k, 2=v (wave-uniform)
        if (which == 0) {
            #pragma unroll
            for (int mi = 0; mi < 4; ++mi)
                #pragma unroll
                for (int ni = 0; ni < 4; ++ni)
                    #pragma unroll
                    for (int r = 0; r < 4; ++r) {
                        const int m = m0 + wr * 64 + mi * 16 + quad * 4 + r;
                        const int nn = (nbase + ni * 16 + l15) & 1023;
                        const int b = m >> 11, s = m & (SEQ - 1);
                        const int h = nn >> 6, d = nn & 63;
                        const float val = (acc[mi][ni][r] + b0[nn]) * qscale;
                        oqh[((size_t)(b * NHEADS + h) * SEQ + s) * DHEAD + d] = f2bf(val);
                    }
        } else if (which == 1) {
            #pragma unroll
            for (int mi = 0; mi < 4; ++mi)
                #pragma unroll
                for (int ni = 0; ni < 4; ++ni)
                    #pragma unroll
                    for (int r = 0; r < 4; ++r) {
                        const int m = m0 + wr * 64 + mi * 16 + quad * 4 + r;
                        const int nn = (nbase + ni * 16 + l15) & 1023;
                        const int b = m >> 11, s = m & (SEQ - 1);
                        const int h = nn >> 6, d = nn & 63;
                        const float val = acc[mi][ni][r] + b1[nn];
                        const short hi = f2bf(val);
                        const size_t idx = ((size_t)(b * NHEADS + h) * SEQ + s) * DHEAD + d;
                        okh[idx] = hi;
                        okl[idx] = f2bf(val - bf2f(hi));
                    }
        } else {
            // V: write bf16-hi transposed [B,H,64,S], 4 consecutive s per 8B store
            #pragma unroll
            for (int mi = 0; mi < 4; ++mi) {
                const int mb = m0 + wr * 64 + mi * 16 + quad * 4;
                const int b = mb >> 11, s0 = mb & (SEQ - 1);
                #pragma unroll
                for (int ni = 0; ni < 4; ++ni) {
                    const int nn = (nbase + ni * 16 + l15) & 1023;
                    const int h = nn >> 6, d = nn & 63;
                    bf16x4 H;
                    #pragma unroll
                    for (int r = 0; r < 4; ++r)
                        H[r] = f2bf(acc[mi][ni][r] + b2[nn]);
                    const size_t idx = ((size_t)(b * NHEADS + h) * DHEAD + d) * SEQ + s0;
                    *(bf16x4*)(ovh + idx) = H;
                }
            }
        }
    }
}

// ---------------- MFMA flash attention v3 ----------------
// Q bf16-hi, K bf16 hi/lo, Vt bf16-hi [B,H,64,S]. No-max base-2 softmax
// (scores bounded << 127, fp32 exp2 cannot overflow; pH shift-invariant).
// l-reduction deferred to epilogue. global_load_lds + XOR-8 chunk swizzle.
// Output bf16 hi/lo in GEMM-A layout [b*S+q][h*64+d].
#define PP 72   // P tile row pad (shorts)

__global__ __launch_bounds__(256) void attn_mfma(
    const short* __restrict__ Qh_g,
    const short* __restrict__ Kh_g, const short* __restrict__ Kl_g,
    const short* __restrict__ Vth_g,
    short* __restrict__ Oh_g, short* __restrict__ Ol_g)
{
    __shared__ short Ksh[4096], Ksl[4096];   // [key][d] 64x64, swizzled
    __shared__ short Vsh[4096];              // [d][s]  64x64, swizzled
    __shared__ short Ph[4][16 * PP];         // per-wave P tile

    const int tid  = threadIdx.x;
    const int lane = tid & 63;
    const int w    = tid >> 6;
    const int quad = lane >> 4;
    const int l15  = lane & 15;

    const int qtile = blockIdx.x & 31;
    const int bh    = blockIdx.x >> 5;
    const int q0    = qtile * 64 + w * 16;
    const size_t kvb = (size_t)bh * SEQ * DHEAD;

    // ---- Q fragments (hi only) ----
    bf16x8 qhi[2];
    {
        const size_t qr = kvb + (size_t)(q0 + l15) * DHEAD;
        qhi[0] = *(const bf16x8*)(Qh_g + qr + quad * 8);
        qhi[1] = *(const bf16x8*)(Qh_g + qr + 32 + quad * 8);
    }

    // staging: w0->Ksh, w1->Ksl, w2->Vsh[j<4], w3->Vsh[j>=4]
    short* dst = (w == 0) ? Ksh : (w == 1) ? Ksl : Vsh;

    f32x4 o[4] = {};
    float l_run[4] = {0.f, 0.f, 0.f, 0.f};

    for (int kb = 0; kb < SEQ; kb += 64) {
        __syncthreads();
        {
            const short* src = (w == 0) ? (Kh_g + kvb + (size_t)kb * DHEAD)
                             : (w == 1) ? (Kl_g + kvb + (size_t)kb * DHEAD)
                                        : (Vth_g + kvb + kb);
            const bool isv = (w >= 2);
            #pragma unroll
            for (int j = 0; j < 8; ++j) {
                const bool act = (w < 2) || (w == 2 && j < 4) || (w == 3 && j >= 4);
                if (act) {
                    const int c = j * 64 + lane;
                    const int row = c >> 3, pos = c & 7;
                    const int gq = pos ^ (row & 7);
                    const short* g = src + (isv ? ((size_t)row * SEQ + gq * 8)
                                                : ((size_t)row * DHEAD + gq * 8));
                    async_ld16(g, dst + j * 512);
                }
            }
        }
        __syncthreads();

        // ---- S = Q K^T (Q-hi x K-hi/lo) ----
        f32x4 sc[4] = {};
        #pragma unroll
        for (int nf = 0; nf < 4; ++nf) {
            const int row = nf * 16 + l15;
            const int sw = row & 7;
            const int o0 = row * 64 + ((quad ^ sw) * 8);
            const int o1 = row * 64 + (((4 + quad) ^ sw) * 8);
            bf16x8 kh0 = *(const bf16x8*)(Ksh + o0);
            bf16x8 kh1 = *(const bf16x8*)(Ksh + o1);
            bf16x8 kl0 = *(const bf16x8*)(Ksl + o0);
            bf16x8 kl1 = *(const bf16x8*)(Ksl + o1);
            f32x4 c = sc[nf];
            c = __builtin_amdgcn_mfma_f32_16x16x32_bf16(qhi[0], kh0, c, 0, 0, 0);
            c = __builtin_amdgcn_mfma_f32_16x16x32_bf16(qhi[1], kh1, c, 0, 0, 0);
            c = __builtin_amdgcn_mfma_f32_16x16x32_bf16(qhi[0], kl0, c, 0, 0, 0);
            c = __builtin_amdgcn_mfma_f32_16x16x32_bf16(qhi[1], kl1, c, 0, 0, 0);
            sc[nf] = c;
        }

        // ---- softmax weights, no max-shift (bounded scores), lane-local l ----
        #pragma unroll
        for (int nf = 0; nf < 4; ++nf) {
            #pragma unroll
            for (int r = 0; r < 4; ++r) {
                const float p = exp2f(sc[nf][r]);
                l_run[r] += p;
                Ph[w][(quad * 4 + r) * PP + nf * 16 + l15] = f2bf(p);
            }
        }
        // wave-private LDS: in-order within wave, no barrier needed

        bf16x8 ph0 = *(const bf16x8*)(&Ph[w][l15 * PP + quad * 8]);
        bf16x8 ph1 = *(const bf16x8*)(&Ph[w][l15 * PP + 32 + quad * 8]);

        // ---- O += P V ----
        #pragma unroll
        for (int nf = 0; nf < 4; ++nf) {
            const int row = nf * 16 + l15;
            const int sw = row & 7;
            const int o0 = row * 64 + ((quad ^ sw) * 8);
            const int o1 = row * 64 + (((4 + quad) ^ sw) * 8);
            bf16x8 vh0 = *(const bf16x8*)(Vsh + o0);
            bf16x8 vh1 = *(const bf16x8*)(Vsh + o1);
            f32x4 c = o[nf];
            c = __builtin_amdgcn_mfma_f32_16x16x32_bf16(ph0, vh0, c, 0, 0, 0);
            c = __builtin_amdgcn_mfma_f32_16x16x32_bf16(ph1, vh1, c, 0, 0, 0);
            o[nf] = c;
        }
    }

    // ---- epilogue: reduce l across the 16 lanes sharing each row, write O ----
    float li[4];
    #pragma unroll
    for (int r = 0; r < 4; ++r) {
        float ls = l_run[r];
        ls += __shfl_xor(ls, 1, 64);
        ls += __shfl_xor(ls, 2, 64);
        ls += __shfl_xor(ls, 4, 64);
        ls += __shfl_xor(ls, 8, 64);
        li[r] = 1.0f / ls;
    }
    const int b = bh >> 4, hh = bh & 15;
    #pragma unroll
    for (int nf = 0; nf < 4; ++nf) {
        #pragma unroll
        for (int r = 0; r < 4; ++r) {
            const int q = q0 + quad * 4 + r;
            const int d = nf * 16 + l15;
            const float val = o[nf][r] * li[r];
            const short hi = f2bf(val);
            const size_t idx = (size_t)(b * SEQ + q) * DMODEL + hh * DHEAD + d;
            Oh_g[idx] = hi;
            Ol_g[idx] = f2bf(val - bf2f(hi));
        }
    }
}

// ---------------- launch ----------------
extern "C" void kernel_launch(void* const* d_in, const int* in_sizes, int n_in,
                              void* d_out, int out_size, void* d_ws, size_t ws_size,
                              hipStream_t stream) {
    const float* x  = (const float*)d_in[0];
    // d_in[1] = pH : softmax shift-invariant, ignored
    const float* Wq = (const float*)d_in[2];
    const float* bq = (const float*)d_in[3];
    const float* Wk = (const float*)d_in[4];
    const float* bk = (const float*)d_in[5];
    const float* Wv = (const float*)d_in[6];
    const float* bv = (const float*)d_in[7];
    const float* Wo = (const float*)d_in[8];
    const float* bo = (const float*)d_in[9];
    float* out = (float*)d_out;

    char* ws = (char*)d_ws;
    const size_t MB = 1024 * 1024;
    short* qh = (short*)(ws + 0 * MB);       // 8 MB
    short* kh = (short*)(ws + 16 * MB);
    short* kl = (short*)(ws + 24 * MB);
    short* vth = (short*)(ws + 32 * MB);
    short* aoh = (short*)(ws + 48 * MB);
    short* aol = (short*)(ws + 56 * MB);
    short* xhi = (short*)(ws + 64 * MB);
    short* xlo = (short*)(ws + 72 * MB);
    short* wqkv_hi = (short*)(ws + 80 * MB); // 6 MB [3072][1024]
    short* wqkv_lo = (short*)(ws + 86 * MB);
    short* wto_hi  = (short*)(ws + 92 * MB); // 2 MB
    short* wto_lo  = (short*)(ws + 94 * MB);

    dim3 blk(256);
    const int n8 = MROWS * DMODEL / 8;

    hipLaunchKernelGGL(convert_hl, dim3(n8 / 256), blk, 0, stream, x, xhi, xlo, n8);

    dim3 tgrid(16, 16);
    hipLaunchKernelGGL(transpose_w, tgrid, blk, 0, stream, Wq, wqkv_hi, wqkv_lo);
    hipLaunchKernelGGL(transpose_w, tgrid, blk, 0, stream, Wk, wqkv_hi + 1024 * 1024, wqkv_lo + 1024 * 1024);
    hipLaunchKernelGGL(transpose_w, tgrid, blk, 0, stream, Wv, wqkv_hi + 2 * 1024 * 1024, wqkv_lo + 2 * 1024 * 1024);
    hipLaunchKernelGGL(transpose_w, tgrid, blk, 0, stream, Wo, wto_hi, wto_lo);

    const float qscale = 0.125f * 1.44269504088896f;   // fold 1/sqrt(dh)*log2(e)
    hipLaunchKernelGGL(mfma_gemm, dim3(3072 / 128, MROWS / 128), blk, 0, stream,
                       xhi, xlo, wqkv_hi, wqkv_lo, bq, bk, bv,
                       qh, kh, kl, vth, (float*)nullptr, 0, qscale);

    hipLaunchKernelGGL(attn_mfma, dim3(BATCH * NHEADS * (SEQ / 64)), blk, 0, stream,
                       qh, kh, kl, vth, aoh, aol);

    hipLaunchKernelGGL(mfma_gemm, dim3(1024 / 128, MROWS / 128), blk, 0, stream,
                       aoh, aol, wto_hi, wto_lo, bo, bo, bo,
                       (short*)nullptr, (short*)nullptr, (short*)nullptr, (short*)nullptr,
                       out, 1, 1.0f);
}

// Round 6
// 262.067 us; speedup vs baseline: 6.8891x; 1.2751x over previous
//
#include <hip/hip_runtime.h>
#include <hip/hip_bf16.h>
#include <math.h>

// Problem constants
#define BATCH 2
#define SEQ   2048
#define DMODEL 1024
#define NHEADS 16
#define DHEAD 64
#define MROWS (BATCH*SEQ)   // 4096

typedef __attribute__((ext_vector_type(8))) short bf16x8;
typedef __attribute__((ext_vector_type(4))) short bf16x4;
typedef __attribute__((ext_vector_type(4))) float f32x4;

__device__ __forceinline__ short f2bf(float f) {   // RNE float->bf16
    union { float f; unsigned u; } c; c.f = f;
    unsigned r = (c.u + 0x7fffu + ((c.u >> 16) & 1u)) >> 16;
    return (short)r;
}
__device__ __forceinline__ float bf2f(short h) {
    union { unsigned u; float f; } c; c.u = ((unsigned)(unsigned short)h) << 16;
    return c.f;
}

__device__ __forceinline__ void async_ld16(const void* g, void* l) {
    __builtin_amdgcn_global_load_lds(
        (const __attribute__((address_space(1))) unsigned*)g,
        (__attribute__((address_space(3))) unsigned*)l, 16, 0, 0);
}

// ---------------- convert: fp32 -> bf16 hi/lo (8 elems/thread) ----------------
__global__ __launch_bounds__(256) void convert_hl(
    const float* __restrict__ in, short* __restrict__ hi, short* __restrict__ lo, int n8)
{
    const int i = blockIdx.x * 256 + threadIdx.x;
    if (i >= n8) return;
    const float4* p = (const float4*)in + (size_t)i * 2;
    float4 a = p[0], b = p[1];
    float v[8] = {a.x, a.y, a.z, a.w, b.x, b.y, b.z, b.w};
    bf16x8 H, L;
    #pragma unroll
    for (int j = 0; j < 8; ++j) {
        short h = f2bf(v[j]);
        H[j] = h;
        L[j] = f2bf(v[j] - bf2f(h));
    }
    *((bf16x8*)hi + i) = H;
    *((bf16x8*)lo + i) = L;
}

// ---------------- fused transpose+convert, hi only: W[1024][1024] -> Wt[N][K] bf16 ----------------
// z = 0..2: Wq/Wk/Wv -> wqkv + z*1M ; z = 3: Wo -> wto
__global__ __launch_bounds__(256) void transpose_w4(
    const float* __restrict__ W0, const float* __restrict__ W1,
    const float* __restrict__ W2, const float* __restrict__ W3,
    short* __restrict__ oqkv, short* __restrict__ oo)
{
    __shared__ float T[64][65];
    const int tid = threadIdx.x;
    const int z = blockIdx.z;
    const float* W = (z == 0) ? W0 : (z == 1) ? W1 : (z == 2) ? W2 : W3;
    short* out = (z < 3) ? (oqkv + (size_t)z * 1024 * 1024) : oo;
    const int n0 = blockIdx.x * 64, k0 = blockIdx.y * 64;
    #pragma unroll
    for (int i = 0; i < 16; ++i) {
        const int idx = tid + i * 256;
        const int r = idx >> 6, c = idx & 63;
        T[r][c] = W[(size_t)(k0 + r) * DMODEL + n0 + c];
    }
    __syncthreads();
    #pragma unroll
    for (int i = 0; i < 4; ++i) {
        const int idx = tid + i * 256;
        const int r = idx >> 4, g = idx & 15;    // out row n0+r, k-group g
        bf16x4 H;
        #pragma unroll
        for (int j = 0; j < 4; ++j)
            H[j] = f2bf(T[g * 4 + j][r]);
        *(bf16x4*)(out + (size_t)(n0 + r) * DMODEL + k0 + g * 4) = H;
    }
}

// ---------------- MFMA GEMM: C = A[M,K] * Bt[N,K]^T, 2-term (Ah*Bh + Al*Bh) ----------------
// 128x128 tile, GBK=64, XOR-8 swizzled LDS (conflict-free b128 reads), 16 K-steps.
// mode 0: emit q bf16 [B,H,S,64] (w/ qscale), k bf16 [B,H,S,64], v bf16 transposed [B,H,64,S]
// mode 1: row-major fp32 [M,1024] + bias
#define GBK 64

__global__ __launch_bounds__(256) void mfma_gemm(
    const short* __restrict__ Ahi, const short* __restrict__ Alo,
    const short* __restrict__ Bthi,
    const float* __restrict__ b0, const float* __restrict__ b1, const float* __restrict__ b2,
    short* __restrict__ oqh, short* __restrict__ okh, short* __restrict__ ovh,
    float* __restrict__ outf, int mode, float qscale)
{
    __shared__ short Ah[128 * GBK], Al[128 * GBK], Bh[128 * GBK];   // 16 KB each

    const int tid  = threadIdx.x;
    const int lane = tid & 63;
    const int w    = tid >> 6;
    const int quad = lane >> 4;
    const int l15  = lane & 15;
    const int wr   = w >> 1, wc = w & 1;
    const int m0   = blockIdx.y * 128;
    const int n0   = blockIdx.x * 128;
    const int K    = DMODEL;

    f32x4 acc[4][4] = {};

    // staging: 1024 chunks (16B) per buffer; wave w owns chunks [w*256, w*256+256)
    // of each buffer; 4 calls per buffer. XOR-8 swizzle on global side.
    int srow[4], spos[4];
    #pragma unroll
    for (int j = 0; j < 4; ++j) {
        const int c = w * 256 + j * 64 + lane;
        srow[j] = c >> 3;
        spos[j] = (c & 7) ^ (srow[j] & 7);
    }

    for (int k0 = 0; k0 < K; k0 += GBK) {
        __syncthreads();
        #pragma unroll
        for (int j = 0; j < 4; ++j) {
            const int cB = (w * 256 + j * 64) * 8;   // LDS short offset (wave-uniform)
            const size_t ga = (size_t)(m0 + srow[j]) * K + k0 + spos[j] * 8;
            const size_t gb = (size_t)(n0 + srow[j]) * K + k0 + spos[j] * 8;
            async_ld16(Ahi + ga, Ah + cB);
            async_ld16(Alo + ga, Al + cB);
            async_ld16(Bthi + gb, Bh + cB);
        }
        __syncthreads();

        #pragma unroll
        for (int s = 0; s < 2; ++s) {
            bf16x8 afh[4], afl[4], bfh[4];
            #pragma unroll
            for (int mi = 0; mi < 4; ++mi) {
                const int row = wr * 64 + mi * 16 + l15;
                const int pos = (s * 4 + quad) ^ (row & 7);
                afh[mi] = *(const bf16x8*)(Ah + row * GBK + pos * 8);
                afl[mi] = *(const bf16x8*)(Al + row * GBK + pos * 8);
            }
            #pragma unroll
            for (int ni = 0; ni < 4; ++ni) {
                const int row = wc * 64 + ni * 16 + l15;
                const int pos = (s * 4 + quad) ^ (row & 7);
                bfh[ni] = *(const bf16x8*)(Bh + row * GBK + pos * 8);
            }
            #pragma unroll
            for (int mi = 0; mi < 4; ++mi)
                #pragma unroll
                for (int ni = 0; ni < 4; ++ni) {
                    f32x4 c = acc[mi][ni];
                    c = __builtin_amdgcn_mfma_f32_16x16x32_bf16(afh[mi], bfh[ni], c, 0, 0, 0);
                    c = __builtin_amdgcn_mfma_f32_16x16x32_bf16(afl[mi], bfh[ni], c, 0, 0, 0);
                    acc[mi][ni] = c;
                }
        }
    }

    const int nbase = n0 + wc * 64;
    if (mode == 1) {
        #pragma unroll
        for (int mi = 0; mi < 4; ++mi)
            #pragma unroll
            for (int ni = 0; ni < 4; ++ni)
                #pragma unroll
                for (int r = 0; r < 4; ++r) {
                    const int m = m0 + wr * 64 + mi * 16 + quad * 4 + r;
                    const int nn = nbase + ni * 16 + l15;
                    outf[(size_t)m * DMODEL + nn] = acc[mi][ni][r] + b0[nn];
                }
    } else {
        const int which = nbase >> 10;               // 0=q, 1=k, 2=v (wave-uniform)
        if (which < 2) {
            const float* bias = which ? b1 : b0;
            short* dst = which ? okh : oqh;
            const float scl = which ? 1.0f : qscale;
            #pragma unroll
            for (int mi = 0; mi < 4; ++mi)
                #pragma unroll
                for (int ni = 0; ni < 4; ++ni)
                    #pragma unroll
                    for (int r = 0; r < 4; ++r) {
                        const int m = m0 + wr * 64 + mi * 16 + quad * 4 + r;
                        const int nn = (nbase + ni * 16 + l15) & 1023;
                        const int b = m >> 11, s = m & (SEQ - 1);
                        const int h = nn >> 6, d = nn & 63;
                        dst[((size_t)(b * NHEADS + h) * SEQ + s) * DHEAD + d] =
                            f2bf((acc[mi][ni][r] + bias[nn]) * scl);
                    }
        } else {
            // V: bf16 transposed [B,H,64,S], 4 consecutive s per 8B store
            #pragma unroll
            for (int mi = 0; mi < 4; ++mi) {
                const int mb = m0 + wr * 64 + mi * 16 + quad * 4;
                const int b = mb >> 11, s0 = mb & (SEQ - 1);
                #pragma unroll
                for (int ni = 0; ni < 4; ++ni) {
                    const int nn = (nbase + ni * 16 + l15) & 1023;
                    const int h = nn >> 6, d = nn & 63;
                    bf16x4 H;
                    #pragma unroll
                    for (int r = 0; r < 4; ++r)
                        H[r] = f2bf(acc[mi][ni][r] + b2[nn]);
                    *(bf16x4*)(ovh + ((size_t)(b * NHEADS + h) * DHEAD + d) * SEQ + s0) = H;
                }
            }
        }
    }
}

// ---------------- MFMA flash attention v4 ----------------
// Q,K,Vt all bf16-hi. No-max base-2 softmax (bounded scores; pH shift-invariant).
// Deferred l-reduction. global_load_lds + XOR-8 swizzle. 16 MFMA/iter.
#define PP 72

__global__ __launch_bounds__(256) void attn_mfma(
    const short* __restrict__ Qh_g, const short* __restrict__ Kh_g,
    const short* __restrict__ Vth_g,
    short* __restrict__ Oh_g, short* __restrict__ Ol_g)
{
    __shared__ short Ksh[4096];     // [key][d] 64x64, swizzled
    __shared__ short Vsh[4096];     // [d][s]  64x64, swizzled
    __shared__ short Ph[4][16 * PP];

    const int tid  = threadIdx.x;
    const int lane = tid & 63;
    const int w    = tid >> 6;
    const int quad = lane >> 4;
    const int l15  = lane & 15;

    const int qtile = blockIdx.x & 31;
    const int bh    = blockIdx.x >> 5;
    const int q0    = qtile * 64 + w * 16;
    const size_t kvb = (size_t)bh * SEQ * DHEAD;

    bf16x8 qhi[2];
    {
        const size_t qr = kvb + (size_t)(q0 + l15) * DHEAD;
        qhi[0] = *(const bf16x8*)(Qh_g + qr + quad * 8);
        qhi[1] = *(const bf16x8*)(Qh_g + qr + 32 + quad * 8);
    }

    // staging: w0/w1 split Ksh, w2/w3 split Vsh; 4 calls each
    short* dst = (w < 2) ? Ksh : Vsh;
    const bool isv = (w >= 2);
    int srow[4], spos[4];
    #pragma unroll
    for (int j = 0; j < 4; ++j) {
        const int c = (w & 1) * 256 + j * 64 + lane;
        srow[j] = c >> 3;
        spos[j] = (c & 7) ^ (srow[j] & 7);
    }

    f32x4 o[4] = {};
    float l_run[4] = {0.f, 0.f, 0.f, 0.f};

    for (int kb = 0; kb < SEQ; kb += 64) {
        __syncthreads();
        {
            const short* src = isv ? (Vth_g + kvb + kb) : (Kh_g + kvb + (size_t)kb * DHEAD);
            #pragma unroll
            for (int j = 0; j < 4; ++j) {
                const short* g = src + (isv ? ((size_t)srow[j] * SEQ + spos[j] * 8)
                                            : ((size_t)srow[j] * DHEAD + spos[j] * 8));
                async_ld16(g, dst + ((w & 1) * 256 + j * 64) * 8);
            }
        }
        __syncthreads();

        // ---- S = Q K^T ----
        f32x4 sc[4] = {};
        #pragma unroll
        for (int nf = 0; nf < 4; ++nf) {
            const int row = nf * 16 + l15;
            const int sw = row & 7;
            bf16x8 kh0 = *(const bf16x8*)(Ksh + row * 64 + ((quad ^ sw) * 8));
            bf16x8 kh1 = *(const bf16x8*)(Ksh + row * 64 + (((4 + quad) ^ sw) * 8));
            f32x4 c = sc[nf];
            c = __builtin_amdgcn_mfma_f32_16x16x32_bf16(qhi[0], kh0, c, 0, 0, 0);
            c = __builtin_amdgcn_mfma_f32_16x16x32_bf16(qhi[1], kh1, c, 0, 0, 0);
            sc[nf] = c;
        }

        // ---- weights, no max-shift; lane-local l ----
        #pragma unroll
        for (int nf = 0; nf < 4; ++nf) {
            #pragma unroll
            for (int r = 0; r < 4; ++r) {
                const float p = exp2f(sc[nf][r]);
                l_run[r] += p;
                Ph[w][(quad * 4 + r) * PP + nf * 16 + l15] = f2bf(p);
            }
        }
        // wave-private LDS: in-order within wave, no barrier needed

        bf16x8 ph0 = *(const bf16x8*)(&Ph[w][l15 * PP + quad * 8]);
        bf16x8 ph1 = *(const bf16x8*)(&Ph[w][l15 * PP + 32 + quad * 8]);

        // ---- O += P V ----
        #pragma unroll
        for (int nf = 0; nf < 4; ++nf) {
            const int row = nf * 16 + l15;
            const int sw = row & 7;
            bf16x8 vh0 = *(const bf16x8*)(Vsh + row * 64 + ((quad ^ sw) * 8));
            bf16x8 vh1 = *(const bf16x8*)(Vsh + row * 64 + (((4 + quad) ^ sw) * 8));
            f32x4 c = o[nf];
            c = __builtin_amdgcn_mfma_f32_16x16x32_bf16(ph0, vh0, c, 0, 0, 0);
            c = __builtin_amdgcn_mfma_f32_16x16x32_bf16(ph1, vh1, c, 0, 0, 0);
            o[nf] = c;
        }
    }

    // ---- epilogue ----
    float li[4];
    #pragma unroll
    for (int r = 0; r < 4; ++r) {
        float ls = l_run[r];
        ls += __shfl_xor(ls, 1, 64);
        ls += __shfl_xor(ls, 2, 64);
        ls += __shfl_xor(ls, 4, 64);
        ls += __shfl_xor(ls, 8, 64);
        li[r] = 1.0f / ls;
    }
    const int b = bh >> 4, hh = bh & 15;
    #pragma unroll
    for (int nf = 0; nf < 4; ++nf) {
        #pragma unroll
        for (int r = 0; r < 4; ++r) {
            const int q = q0 + quad * 4 + r;
            const int d = nf * 16 + l15;
            const float val = o[nf][r] * li[r];
            const short hi = f2bf(val);
            const size_t idx = (size_t)(b * SEQ + q) * DMODEL + hh * DHEAD + d;
            Oh_g[idx] = hi;
            Ol_g[idx] = f2bf(val - bf2f(hi));
        }
    }
}

// ---------------- launch ----------------
extern "C" void kernel_launch(void* const* d_in, const int* in_sizes, int n_in,
                              void* d_out, int out_size, void* d_ws, size_t ws_size,
                              hipStream_t stream) {
    const float* x  = (const float*)d_in[0];
    // d_in[1] = pH : softmax shift-invariant, ignored
    const float* Wq = (const float*)d_in[2];
    const float* bq = (const float*)d_in[3];
    const float* Wk = (const float*)d_in[4];
    const float* bk = (const float*)d_in[5];
    const float* Wv = (const float*)d_in[6];
    const float* bv = (const float*)d_in[7];
    const float* Wo = (const float*)d_in[8];
    const float* bo = (const float*)d_in[9];
    float* out = (float*)d_out;

    char* ws = (char*)d_ws;
    const size_t MB = 1024 * 1024;
    short* qh  = (short*)(ws + 0 * MB);      // 8 MB
    short* kh  = (short*)(ws + 16 * MB);     // 8 MB
    short* vth = (short*)(ws + 32 * MB);     // 8 MB
    short* aoh = (short*)(ws + 48 * MB);     // 8 MB
    short* aol = (short*)(ws + 56 * MB);     // 8 MB
    short* xhi = (short*)(ws + 64 * MB);     // 8 MB
    short* xlo = (short*)(ws + 72 * MB);     // 8 MB
    short* wqkv_hi = (short*)(ws + 80 * MB); // 6 MB [3072][1024]
    short* wto_hi  = (short*)(ws + 92 * MB); // 2 MB

    dim3 blk(256);
    const int n8 = MROWS * DMODEL / 8;

    hipLaunchKernelGGL(convert_hl, dim3(n8 / 256), blk, 0, stream, x, xhi, xlo, n8);
    hipLaunchKernelGGL(transpose_w4, dim3(16, 16, 4), blk, 0, stream,
                       Wq, Wk, Wv, Wo, wqkv_hi, wto_hi);

    const float qscale = 0.125f * 1.44269504088896f;   // fold 1/sqrt(dh)*log2(e)
    hipLaunchKernelGGL(mfma_gemm, dim3(3072 / 128, MROWS / 128), blk, 0, stream,
                       xhi, xlo, wqkv_hi, bq, bk, bv,
                       qh, kh, vth, (float*)nullptr, 0, qscale);

    hipLaunchKernelGGL(attn_mfma, dim3(BATCH * NHEADS * (SEQ / 64)), blk, 0, stream,
                       qh, kh, vth, aoh, aol);

    hipLaunchKernelGGL(mfma_gemm, dim3(1024 / 128, MROWS / 128), blk, 0, stream,
                       aoh, aol, wto_hi, bo, bo, bo,
                       (short*)nullptr, (short*)nullptr, (short*)nullptr,
                       out, 1, 1.0f);
}

// Round 7
// 227.243 us; speedup vs baseline: 7.9448x; 1.1532x over previous
//
#include <hip/hip_runtime.h>
#include <hip/hip_bf16.h>
#include <math.h>

// Problem constants
#define BATCH 2
#define SEQ   2048
#define DMODEL 1024
#define NHEADS 16
#define DHEAD 64
#define MROWS (BATCH*SEQ)   // 4096

typedef __attribute__((ext_vector_type(8))) short bf16x8;
typedef __attribute__((ext_vector_type(4))) short bf16x4;
typedef __attribute__((ext_vector_type(4))) float f32x4;

__device__ __forceinline__ short f2bf(float f) {   // RNE float->bf16
    union { float f; unsigned u; } c; c.f = f;
    unsigned r = (c.u + 0x7fffu + ((c.u >> 16) & 1u)) >> 16;
    return (short)r;
}
__device__ __forceinline__ float truncmask(unsigned u) {  // bf16-trunc value as f32
    union { unsigned u; float f; } c; c.u = u & 0xffff0000u;
    return c.f;
}

__device__ __forceinline__ void async_ld16(const void* g, void* l) {
    __builtin_amdgcn_global_load_lds(
        (const __attribute__((address_space(1))) unsigned*)g,
        (__attribute__((address_space(3))) unsigned*)l, 16, 0, 0);
}

// ---------------- convert: fp32 -> bf16 hi (8 elems/thread) ----------------
__global__ __launch_bounds__(256) void convert_h(
    const float* __restrict__ in, short* __restrict__ hi, int n8)
{
    const int i = blockIdx.x * 256 + threadIdx.x;
    if (i >= n8) return;
    const float4* p = (const float4*)in + (size_t)i * 2;
    float4 a = p[0], b = p[1];
    float v[8] = {a.x, a.y, a.z, a.w, b.x, b.y, b.z, b.w};
    bf16x8 H;
    #pragma unroll
    for (int j = 0; j < 8; ++j) H[j] = f2bf(v[j]);
    *((bf16x8*)hi + i) = H;
}

// ---------------- fused transpose+convert, hi only: W[1024][1024] -> Wt[N][K] bf16 ----------------
__global__ __launch_bounds__(256) void transpose_w4(
    const float* __restrict__ W0, const float* __restrict__ W1,
    const float* __restrict__ W2, const float* __restrict__ W3,
    short* __restrict__ oqkv, short* __restrict__ oo)
{
    __shared__ float T[64][65];
    const int tid = threadIdx.x;
    const int z = blockIdx.z;
    const float* W = (z == 0) ? W0 : (z == 1) ? W1 : (z == 2) ? W2 : W3;
    short* out = (z < 3) ? (oqkv + (size_t)z * 1024 * 1024) : oo;
    const int n0 = blockIdx.x * 64, k0 = blockIdx.y * 64;
    #pragma unroll
    for (int i = 0; i < 16; ++i) {
        const int idx = tid + i * 256;
        const int r = idx >> 6, c = idx & 63;
        T[r][c] = W[(size_t)(k0 + r) * DMODEL + n0 + c];
    }
    __syncthreads();
    #pragma unroll
    for (int i = 0; i < 4; ++i) {
        const int idx = tid + i * 256;
        const int r = idx >> 4, g = idx & 15;
        bf16x4 H;
        #pragma unroll
        for (int j = 0; j < 4; ++j)
            H[j] = f2bf(T[g * 4 + j][r]);
        *(bf16x4*)(out + (size_t)(n0 + r) * DMODEL + k0 + g * 4) = H;
    }
}

// ---------------- MFMA GEMM: C = A[M,K] * Bt[N,K]^T, 1-term bf16 ----------------
// 128x128 tile, GBK=64, XOR-8 swizzled LDS, 16 K-steps.
// mode 0: emit q bf16 [B,H,S,64] (w/ qscale), k bf16 [B,H,S,64], v bf16 transposed [B,H,64,S]
// mode 1: row-major fp32 [M,1024] + bias
#define GBK 64

__global__ __launch_bounds__(256) void mfma_gemm(
    const short* __restrict__ Ahi, const short* __restrict__ Bthi,
    const float* __restrict__ b0, const float* __restrict__ b1, const float* __restrict__ b2,
    short* __restrict__ oqh, short* __restrict__ okh, short* __restrict__ ovh,
    float* __restrict__ outf, int mode, float qscale)
{
    __shared__ short Ah[128 * GBK], Bh[128 * GBK];   // 16 KB each

    const int tid  = threadIdx.x;
    const int lane = tid & 63;
    const int w    = tid >> 6;
    const int quad = lane >> 4;
    const int l15  = lane & 15;
    const int wr   = w >> 1, wc = w & 1;
    const int m0   = blockIdx.y * 128;
    const int n0   = blockIdx.x * 128;
    const int K    = DMODEL;

    f32x4 acc[4][4] = {};

    int srow[4], spos[4];
    #pragma unroll
    for (int j = 0; j < 4; ++j) {
        const int c = w * 256 + j * 64 + lane;
        srow[j] = c >> 3;
        spos[j] = (c & 7) ^ (srow[j] & 7);
    }

    for (int k0 = 0; k0 < K; k0 += GBK) {
        __syncthreads();
        #pragma unroll
        for (int j = 0; j < 4; ++j) {
            const int cB = (w * 256 + j * 64) * 8;
            async_ld16(Ahi + (size_t)(m0 + srow[j]) * K + k0 + spos[j] * 8, Ah + cB);
            async_ld16(Bthi + (size_t)(n0 + srow[j]) * K + k0 + spos[j] * 8, Bh + cB);
        }
        __syncthreads();

        #pragma unroll
        for (int s = 0; s < 2; ++s) {
            bf16x8 afh[4], bfh[4];
            #pragma unroll
            for (int mi = 0; mi < 4; ++mi) {
                const int row = wr * 64 + mi * 16 + l15;
                const int pos = (s * 4 + quad) ^ (row & 7);
                afh[mi] = *(const bf16x8*)(Ah + row * GBK + pos * 8);
            }
            #pragma unroll
            for (int ni = 0; ni < 4; ++ni) {
                const int row = wc * 64 + ni * 16 + l15;
                const int pos = (s * 4 + quad) ^ (row & 7);
                bfh[ni] = *(const bf16x8*)(Bh + row * GBK + pos * 8);
            }
            #pragma unroll
            for (int mi = 0; mi < 4; ++mi)
                #pragma unroll
                for (int ni = 0; ni < 4; ++ni)
                    acc[mi][ni] = __builtin_amdgcn_mfma_f32_16x16x32_bf16(
                        afh[mi], bfh[ni], acc[mi][ni], 0, 0, 0);
        }
    }

    const int nbase = n0 + wc * 64;
    if (mode == 1) {
        #pragma unroll
        for (int mi = 0; mi < 4; ++mi)
            #pragma unroll
            for (int ni = 0; ni < 4; ++ni)
                #pragma unroll
                for (int r = 0; r < 4; ++r) {
                    const int m = m0 + wr * 64 + mi * 16 + quad * 4 + r;
                    const int nn = nbase + ni * 16 + l15;
                    outf[(size_t)m * DMODEL + nn] = acc[mi][ni][r] + b0[nn];
                }
    } else {
        const int which = nbase >> 10;               // 0=q, 1=k, 2=v (wave-uniform)
        if (which < 2) {
            const float* bias = which ? b1 : b0;
            short* dst = which ? okh : oqh;
            const float scl = which ? 1.0f : qscale;
            #pragma unroll
            for (int mi = 0; mi < 4; ++mi)
                #pragma unroll
                for (int ni = 0; ni < 4; ++ni)
                    #pragma unroll
                    for (int r = 0; r < 4; ++r) {
                        const int m = m0 + wr * 64 + mi * 16 + quad * 4 + r;
                        const int nn = (nbase + ni * 16 + l15) & 1023;
                        const int b = m >> 11, s = m & (SEQ - 1);
                        const int h = nn >> 6, d = nn & 63;
                        dst[((size_t)(b * NHEADS + h) * SEQ + s) * DHEAD + d] =
                            f2bf((acc[mi][ni][r] + bias[nn]) * scl);
                    }
        } else {
            #pragma unroll
            for (int mi = 0; mi < 4; ++mi) {
                const int mb = m0 + wr * 64 + mi * 16 + quad * 4;
                const int b = mb >> 11, s0 = mb & (SEQ - 1);
                #pragma unroll
                for (int ni = 0; ni < 4; ++ni) {
                    const int nn = (nbase + ni * 16 + l15) & 1023;
                    const int h = nn >> 6, d = nn & 63;
                    bf16x4 H;
                    #pragma unroll
                    for (int r = 0; r < 4; ++r)
                        H[r] = f2bf(acc[mi][ni][r] + b2[nn]);
                    *(bf16x4*)(ovh + ((size_t)(b * NHEADS + h) * DHEAD + d) * SEQ + s0) = H;
                }
            }
        }
    }
}

// ---------------- MFMA flash attention v5 ----------------
// S^T = K*Q^T (operand swap): lane holds 4 CONSECUTIVE keys for one q ->
// P packed via v_perm truncation (2 ops/4 vals) + ds_write_b64.
// l sums the truncated values -> truncation bias cancels in normalization.
// No-max base-2 softmax (bounded scores; pH shift-invariant).
#define PP 72

__global__ __launch_bounds__(256) void attn_mfma(
    const short* __restrict__ Qh_g, const short* __restrict__ Kh_g,
    const short* __restrict__ Vth_g, short* __restrict__ Oh_g)
{
    __shared__ short Ksh[4096];     // [key][d] 64x64, swizzled
    __shared__ short Vsh[4096];     // [d][s]  64x64, swizzled
    __shared__ short Ph[4][16 * PP];

    const int tid  = threadIdx.x;
    const int lane = tid & 63;
    const int w    = tid >> 6;
    const int quad = lane >> 4;
    const int l15  = lane & 15;

    const int qtile = blockIdx.x & 31;
    const int bh    = blockIdx.x >> 5;
    const int q0    = qtile * 64 + w * 16;
    const size_t kvb = (size_t)bh * SEQ * DHEAD;

    bf16x8 qhi[2];
    {
        const size_t qr = kvb + (size_t)(q0 + l15) * DHEAD;
        qhi[0] = *(const bf16x8*)(Qh_g + qr + quad * 8);
        qhi[1] = *(const bf16x8*)(Qh_g + qr + 32 + quad * 8);
    }

    short* dst = (w < 2) ? Ksh : Vsh;
    const bool isv = (w >= 2);
    int srow[4], spos[4];
    #pragma unroll
    for (int j = 0; j < 4; ++j) {
        const int c = (w & 1) * 256 + j * 64 + lane;
        srow[j] = c >> 3;
        spos[j] = (c & 7) ^ (srow[j] & 7);
    }

    f32x4 o[4] = {};
    float l_run = 0.f;

    for (int kb = 0; kb < SEQ; kb += 64) {
        __syncthreads();
        {
            const short* src = isv ? (Vth_g + kvb + kb) : (Kh_g + kvb + (size_t)kb * DHEAD);
            #pragma unroll
            for (int j = 0; j < 4; ++j) {
                const short* g = src + (isv ? ((size_t)srow[j] * SEQ + spos[j] * 8)
                                            : ((size_t)srow[j] * DHEAD + spos[j] * 8));
                async_ld16(g, dst + ((w & 1) * 256 + j * 64) * 8);
            }
        }
        __syncthreads();

        // ---- S^T = K Q^T : frag mf -> keys mf*16+quad*4+{0..3}, q = l15 ----
        #pragma unroll
        for (int mf = 0; mf < 4; ++mf) {
            const int row = mf * 16 + l15;
            const int sw = row & 7;
            bf16x8 kh0 = *(const bf16x8*)(Ksh + row * 64 + ((quad ^ sw) * 8));
            bf16x8 kh1 = *(const bf16x8*)(Ksh + row * 64 + (((4 + quad) ^ sw) * 8));
            f32x4 c = {};
            c = __builtin_amdgcn_mfma_f32_16x16x32_bf16(kh0, qhi[0], c, 0, 0, 0);
            c = __builtin_amdgcn_mfma_f32_16x16x32_bf16(kh1, qhi[1], c, 0, 0, 0);

            // exp2, truncate to bf16 (bias cancels: l sums truncated values)
            unsigned u[4];
            #pragma unroll
            for (int r = 0; r < 4; ++r) {
                union { float f; unsigned u; } p;
                p.f = exp2f(c[r]);
                u[r] = p.u;
                l_run += truncmask(u[r]);
            }
            const unsigned pk01 = __builtin_amdgcn_perm(u[1], u[0], 0x07060302u);
            const unsigned pk23 = __builtin_amdgcn_perm(u[3], u[2], 0x07060302u);
            uint2 pk; pk.x = pk01; pk.y = pk23;
            *(uint2*)(&Ph[w][l15 * PP + mf * 16 + quad * 4]) = pk;
        }
        // wave-private LDS: in-order within wave, no barrier needed

        bf16x8 ph0 = *(const bf16x8*)(&Ph[w][l15 * PP + quad * 8]);
        bf16x8 ph1 = *(const bf16x8*)(&Ph[w][l15 * PP + 32 + quad * 8]);

        // ---- O += P V ----
        #pragma unroll
        for (int nf = 0; nf < 4; ++nf) {
            const int row = nf * 16 + l15;
            const int sw = row & 7;
            bf16x8 vh0 = *(const bf16x8*)(Vsh + row * 64 + ((quad ^ sw) * 8));
            bf16x8 vh1 = *(const bf16x8*)(Vsh + row * 64 + (((4 + quad) ^ sw) * 8));
            f32x4 c = o[nf];
            c = __builtin_amdgcn_mfma_f32_16x16x32_bf16(ph0, vh0, c, 0, 0, 0);
            c = __builtin_amdgcn_mfma_f32_16x16x32_bf16(ph1, vh1, c, 0, 0, 0);
            o[nf] = c;
        }
    }

    // ---- epilogue: l_run holds partial sum for q=l15; reduce across quads ----
    float ls = l_run;
    ls += __shfl_xor(ls, 16, 64);
    ls += __shfl_xor(ls, 32, 64);
    // fetch l for this lane's output rows q = quad*4+r (held at lane quad*4+r)
    float li[4];
    #pragma unroll
    for (int r = 0; r < 4; ++r)
        li[r] = 1.0f / __shfl(ls, quad * 4 + r, 64);

    const int b = bh >> 4, hh = bh & 15;
    #pragma unroll
    for (int nf = 0; nf < 4; ++nf) {
        #pragma unroll
        for (int r = 0; r < 4; ++r) {
            const int q = q0 + quad * 4 + r;
            const int d = nf * 16 + l15;
            Oh_g[(size_t)(b * SEQ + q) * DMODEL + hh * DHEAD + d] = f2bf(o[nf][r] * li[r]);
        }
    }
}

// ---------------- launch ----------------
extern "C" void kernel_launch(void* const* d_in, const int* in_sizes, int n_in,
                              void* d_out, int out_size, void* d_ws, size_t ws_size,
                              hipStream_t stream) {
    const float* x  = (const float*)d_in[0];
    // d_in[1] = pH : softmax shift-invariant, ignored
    const float* Wq = (const float*)d_in[2];
    const float* bq = (const float*)d_in[3];
    const float* Wk = (const float*)d_in[4];
    const float* bk = (const float*)d_in[5];
    const float* Wv = (const float*)d_in[6];
    const float* bv = (const float*)d_in[7];
    const float* Wo = (const float*)d_in[8];
    const float* bo = (const float*)d_in[9];
    float* out = (float*)d_out;

    char* ws = (char*)d_ws;
    const size_t MB = 1024 * 1024;
    short* qh  = (short*)(ws + 0 * MB);      // 8 MB
    short* kh  = (short*)(ws + 16 * MB);     // 8 MB
    short* vth = (short*)(ws + 32 * MB);     // 8 MB
    short* aoh = (short*)(ws + 48 * MB);     // 8 MB
    short* xhi = (short*)(ws + 64 * MB);     // 8 MB
    short* wqkv_hi = (short*)(ws + 80 * MB); // 6 MB [3072][1024]
    short* wto_hi  = (short*)(ws + 92 * MB); // 2 MB

    dim3 blk(256);
    const int n8 = MROWS * DMODEL / 8;

    hipLaunchKernelGGL(convert_h, dim3(n8 / 256), blk, 0, stream, x, xhi, n8);
    hipLaunchKernelGGL(transpose_w4, dim3(16, 16, 4), blk, 0, stream,
                       Wq, Wk, Wv, Wo, wqkv_hi, wto_hi);

    const float qscale = 0.125f * 1.44269504088896f;   // fold 1/sqrt(dh)*log2(e)
    hipLaunchKernelGGL(mfma_gemm, dim3(3072 / 128, MROWS / 128), blk, 0, stream,
                       xhi, wqkv_hi, bq, bk, bv,
                       qh, kh, vth, (float*)nullptr, 0, qscale);

    hipLaunchKernelGGL(attn_mfma, dim3(BATCH * NHEADS * (SEQ / 64)), blk, 0, stream,
                       qh, kh, vth, aoh);

    hipLaunchKernelGGL(mfma_gemm, dim3(1024 / 128, MROWS / 128), blk, 0, stream,
                       aoh, wto_hi, bo, bo, bo,
                       (short*)nullptr, (short*)nullptr, (short*)nullptr,
                       out, 1, 1.0f);
}

// Round 8
// 216.625 us; speedup vs baseline: 8.3342x; 1.0490x over previous
//
#include <hip/hip_runtime.h>
#include <hip/hip_bf16.h>
#include <math.h>

// Problem constants
#define BATCH 2
#define SEQ   2048
#define DMODEL 1024
#define NHEADS 16
#define DHEAD 64
#define MROWS (BATCH*SEQ)   // 4096

typedef __attribute__((ext_vector_type(8))) short bf16x8;
typedef __attribute__((ext_vector_type(4))) short bf16x4;
typedef __attribute__((ext_vector_type(4))) float f32x4;

__device__ __forceinline__ short f2bf(float f) {   // RNE float->bf16
    union { float f; unsigned u; } c; c.f = f;
    unsigned r = (c.u + 0x7fffu + ((c.u >> 16) & 1u)) >> 16;
    return (short)r;
}
__device__ __forceinline__ float truncmask(unsigned u) {  // bf16-trunc value as f32
    union { unsigned u; float f; } c; c.u = u & 0xffff0000u;
    return c.f;
}

__device__ __forceinline__ void async_ld16(const void* g, void* l) {
    __builtin_amdgcn_global_load_lds(
        (const __attribute__((address_space(1))) unsigned*)g,
        (__attribute__((address_space(3))) unsigned*)l, 16, 0, 0);
}

// ---------------- convert: fp32 -> bf16 hi (8 elems/thread) ----------------
__global__ __launch_bounds__(256) void convert_h(
    const float* __restrict__ in, short* __restrict__ hi, int n8)
{
    const int i = blockIdx.x * 256 + threadIdx.x;
    if (i >= n8) return;
    const float4* p = (const float4*)in + (size_t)i * 2;
    float4 a = p[0], b = p[1];
    float v[8] = {a.x, a.y, a.z, a.w, b.x, b.y, b.z, b.w};
    bf16x8 H;
    #pragma unroll
    for (int j = 0; j < 8; ++j) H[j] = f2bf(v[j]);
    *((bf16x8*)hi + i) = H;
}

// ---------------- fused transpose+convert, hi only: W[1024][1024] -> Wt[N][K] bf16 ----------------
__global__ __launch_bounds__(256) void transpose_w4(
    const float* __restrict__ W0, const float* __restrict__ W1,
    const float* __restrict__ W2, const float* __restrict__ W3,
    short* __restrict__ oqkv, short* __restrict__ oo)
{
    __shared__ float T[64][65];
    const int tid = threadIdx.x;
    const int z = blockIdx.z;
    const float* W = (z == 0) ? W0 : (z == 1) ? W1 : (z == 2) ? W2 : W3;
    short* out = (z < 3) ? (oqkv + (size_t)z * 1024 * 1024) : oo;
    const int n0 = blockIdx.x * 64, k0 = blockIdx.y * 64;
    #pragma unroll
    for (int i = 0; i < 16; ++i) {
        const int idx = tid + i * 256;
        const int r = idx >> 6, c = idx & 63;
        T[r][c] = W[(size_t)(k0 + r) * DMODEL + n0 + c];
    }
    __syncthreads();
    #pragma unroll
    for (int i = 0; i < 4; ++i) {
        const int idx = tid + i * 256;
        const int r = idx >> 4, g = idx & 15;
        bf16x4 H;
        #pragma unroll
        for (int j = 0; j < 4; ++j)
            H[j] = f2bf(T[g * 4 + j][r]);
        *(bf16x4*)(out + (size_t)(n0 + r) * DMODEL + k0 + g * 4) = H;
    }
}

// ---------------- MFMA GEMM: C = A[M,K] * Bt[N,K]^T, 1-term bf16 ----------------
#define GBK 64

__global__ __launch_bounds__(256) void mfma_gemm(
    const short* __restrict__ Ahi, const short* __restrict__ Bthi,
    const float* __restrict__ b0, const float* __restrict__ b1, const float* __restrict__ b2,
    short* __restrict__ oqh, short* __restrict__ okh, short* __restrict__ ovh,
    float* __restrict__ outf, int mode, float qscale)
{
    __shared__ short Ah[128 * GBK], Bh[128 * GBK];   // 16 KB each

    const int tid  = threadIdx.x;
    const int lane = tid & 63;
    const int w    = tid >> 6;
    const int quad = lane >> 4;
    const int l15  = lane & 15;
    const int wr   = w >> 1, wc = w & 1;
    const int m0   = blockIdx.y * 128;
    const int n0   = blockIdx.x * 128;
    const int K    = DMODEL;

    f32x4 acc[4][4] = {};

    int srow[4], spos[4];
    #pragma unroll
    for (int j = 0; j < 4; ++j) {
        const int c = w * 256 + j * 64 + lane;
        srow[j] = c >> 3;
        spos[j] = (c & 7) ^ (srow[j] & 7);
    }

    for (int k0 = 0; k0 < K; k0 += GBK) {
        __syncthreads();
        #pragma unroll
        for (int j = 0; j < 4; ++j) {
            const int cB = (w * 256 + j * 64) * 8;
            async_ld16(Ahi + (size_t)(m0 + srow[j]) * K + k0 + spos[j] * 8, Ah + cB);
            async_ld16(Bthi + (size_t)(n0 + srow[j]) * K + k0 + spos[j] * 8, Bh + cB);
        }
        __syncthreads();

        #pragma unroll
        for (int s = 0; s < 2; ++s) {
            bf16x8 afh[4], bfh[4];
            #pragma unroll
            for (int mi = 0; mi < 4; ++mi) {
                const int row = wr * 64 + mi * 16 + l15;
                const int pos = (s * 4 + quad) ^ (row & 7);
                afh[mi] = *(const bf16x8*)(Ah + row * GBK + pos * 8);
            }
            #pragma unroll
            for (int ni = 0; ni < 4; ++ni) {
                const int row = wc * 64 + ni * 16 + l15;
                const int pos = (s * 4 + quad) ^ (row & 7);
                bfh[ni] = *(const bf16x8*)(Bh + row * GBK + pos * 8);
            }
            #pragma unroll
            for (int mi = 0; mi < 4; ++mi)
                #pragma unroll
                for (int ni = 0; ni < 4; ++ni)
                    acc[mi][ni] = __builtin_amdgcn_mfma_f32_16x16x32_bf16(
                        afh[mi], bfh[ni], acc[mi][ni], 0, 0, 0);
        }
    }

    const int nbase = n0 + wc * 64;
    if (mode == 1) {
        #pragma unroll
        for (int mi = 0; mi < 4; ++mi)
            #pragma unroll
            for (int ni = 0; ni < 4; ++ni)
                #pragma unroll
                for (int r = 0; r < 4; ++r) {
                    const int m = m0 + wr * 64 + mi * 16 + quad * 4 + r;
                    const int nn = nbase + ni * 16 + l15;
                    outf[(size_t)m * DMODEL + nn] = acc[mi][ni][r] + b0[nn];
                }
    } else {
        const int which = nbase >> 10;               // 0=q, 1=k, 2=v (wave-uniform)
        if (which < 2) {
            const float* bias = which ? b1 : b0;
            short* dst = which ? okh : oqh;
            const float scl = which ? 1.0f : qscale;
            #pragma unroll
            for (int mi = 0; mi < 4; ++mi)
                #pragma unroll
                for (int ni = 0; ni < 4; ++ni)
                    #pragma unroll
                    for (int r = 0; r < 4; ++r) {
                        const int m = m0 + wr * 64 + mi * 16 + quad * 4 + r;
                        const int nn = (nbase + ni * 16 + l15) & 1023;
                        const int b = m >> 11, s = m & (SEQ - 1);
                        const int h = nn >> 6, d = nn & 63;
                        dst[((size_t)(b * NHEADS + h) * SEQ + s) * DHEAD + d] =
                            f2bf((acc[mi][ni][r] + bias[nn]) * scl);
                    }
        } else {
            #pragma unroll
            for (int mi = 0; mi < 4; ++mi) {
                const int mb = m0 + wr * 64 + mi * 16 + quad * 4;
                const int b = mb >> 11, s0 = mb & (SEQ - 1);
                #pragma unroll
                for (int ni = 0; ni < 4; ++ni) {
                    const int nn = (nbase + ni * 16 + l15) & 1023;
                    const int h = nn >> 6, d = nn & 63;
                    bf16x4 H;
                    #pragma unroll
                    for (int r = 0; r < 4; ++r)
                        H[r] = f2bf(acc[mi][ni][r] + b2[nn]);
                    *(bf16x4*)(ovh + ((size_t)(b * NHEADS + h) * DHEAD + d) * SEQ + s0) = H;
                }
            }
        }
    }
}

// ---------------- MFMA flash attention v6 ----------------
// S^T = K*Q^T; P via v_perm truncation; l sums truncated values (bias cancels).
// Raw v_exp_f32 via __builtin_amdgcn_exp2f (scores bounded -> safe).
// Block mapping: bh = blk&31 so all q-tiles of one head share an XCD
// (blk mod 8 == bh mod 8 under round-robin dispatch) -> K/V L2-resident.
#define PP 72

__global__ __launch_bounds__(256) void attn_mfma(
    const short* __restrict__ Qh_g, const short* __restrict__ Kh_g,
    const short* __restrict__ Vth_g, short* __restrict__ Oh_g)
{
    __shared__ short Ksh[4096];     // [key][d] 64x64, swizzled
    __shared__ short Vsh[4096];     // [d][s]  64x64, swizzled
    __shared__ short Ph[4][16 * PP];

    const int tid  = threadIdx.x;
    const int lane = tid & 63;
    const int w    = tid >> 6;
    const int quad = lane >> 4;
    const int l15  = lane & 15;

    const int bh    = blockIdx.x & 31;       // XCD-local head
    const int qtile = blockIdx.x >> 5;
    const int q0    = qtile * 64 + w * 16;
    const size_t kvb = (size_t)bh * SEQ * DHEAD;

    bf16x8 qhi[2];
    {
        const size_t qr = kvb + (size_t)(q0 + l15) * DHEAD;
        qhi[0] = *(const bf16x8*)(Qh_g + qr + quad * 8);
        qhi[1] = *(const bf16x8*)(Qh_g + qr + 32 + quad * 8);
    }

    short* dst = (w < 2) ? Ksh : Vsh;
    const bool isv = (w >= 2);
    int srow[4], spos[4];
    #pragma unroll
    for (int j = 0; j < 4; ++j) {
        const int c = (w & 1) * 256 + j * 64 + lane;
        srow[j] = c >> 3;
        spos[j] = (c & 7) ^ (srow[j] & 7);
    }

    f32x4 o[4] = {};
    float l_run = 0.f;

    for (int kb = 0; kb < SEQ; kb += 64) {
        __syncthreads();
        {
            const short* src = isv ? (Vth_g + kvb + kb) : (Kh_g + kvb + (size_t)kb * DHEAD);
            #pragma unroll
            for (int j = 0; j < 4; ++j) {
                const short* g = src + (isv ? ((size_t)srow[j] * SEQ + spos[j] * 8)
                                            : ((size_t)srow[j] * DHEAD + spos[j] * 8));
                async_ld16(g, dst + ((w & 1) * 256 + j * 64) * 8);
            }
        }
        __syncthreads();

        // ---- S^T = K Q^T : frag mf -> keys mf*16+quad*4+{0..3}, q = l15 ----
        #pragma unroll
        for (int mf = 0; mf < 4; ++mf) {
            const int row = mf * 16 + l15;
            const int sw = row & 7;
            bf16x8 kh0 = *(const bf16x8*)(Ksh + row * 64 + ((quad ^ sw) * 8));
            bf16x8 kh1 = *(const bf16x8*)(Ksh + row * 64 + (((4 + quad) ^ sw) * 8));
            f32x4 c = {};
            c = __builtin_amdgcn_mfma_f32_16x16x32_bf16(kh0, qhi[0], c, 0, 0, 0);
            c = __builtin_amdgcn_mfma_f32_16x16x32_bf16(kh1, qhi[1], c, 0, 0, 0);

            // raw v_exp_f32; truncate to bf16 (bias cancels: l sums truncated)
            unsigned u[4];
            #pragma unroll
            for (int r = 0; r < 4; ++r) {
                union { float f; unsigned u; } p;
                p.f = __builtin_amdgcn_exp2f(c[r]);
                u[r] = p.u;
                l_run += truncmask(u[r]);
            }
            const unsigned pk01 = __builtin_amdgcn_perm(u[1], u[0], 0x07060302u);
            const unsigned pk23 = __builtin_amdgcn_perm(u[3], u[2], 0x07060302u);
            uint2 pk; pk.x = pk01; pk.y = pk23;
            *(uint2*)(&Ph[w][l15 * PP + mf * 16 + quad * 4]) = pk;
        }
        // wave-private LDS: in-order within wave, no barrier needed

        bf16x8 ph0 = *(const bf16x8*)(&Ph[w][l15 * PP + quad * 8]);
        bf16x8 ph1 = *(const bf16x8*)(&Ph[w][l15 * PP + 32 + quad * 8]);

        // ---- O += P V ----
        #pragma unroll
        for (int nf = 0; nf < 4; ++nf) {
            const int row = nf * 16 + l15;
            const int sw = row & 7;
            bf16x8 vh0 = *(const bf16x8*)(Vsh + row * 64 + ((quad ^ sw) * 8));
            bf16x8 vh1 = *(const bf16x8*)(Vsh + row * 64 + (((4 + quad) ^ sw) * 8));
            f32x4 c = o[nf];
            c = __builtin_amdgcn_mfma_f32_16x16x32_bf16(ph0, vh0, c, 0, 0, 0);
            c = __builtin_amdgcn_mfma_f32_16x16x32_bf16(ph1, vh1, c, 0, 0, 0);
            o[nf] = c;
        }
    }

    // ---- epilogue: l_run holds partial sum for q=l15; reduce across quads ----
    float ls = l_run;
    ls += __shfl_xor(ls, 16, 64);
    ls += __shfl_xor(ls, 32, 64);
    float li[4];
    #pragma unroll
    for (int r = 0; r < 4; ++r)
        li[r] = 1.0f / __shfl(ls, quad * 4 + r, 64);

    const int b = bh >> 4, hh = bh & 15;
    #pragma unroll
    for (int nf = 0; nf < 4; ++nf) {
        #pragma unroll
        for (int r = 0; r < 4; ++r) {
            const int q = q0 + quad * 4 + r;
            const int d = nf * 16 + l15;
            Oh_g[(size_t)(b * SEQ + q) * DMODEL + hh * DHEAD + d] = f2bf(o[nf][r] * li[r]);
        }
    }
}

// ---------------- launch ----------------
extern "C" void kernel_launch(void* const* d_in, const int* in_sizes, int n_in,
                              void* d_out, int out_size, void* d_ws, size_t ws_size,
                              hipStream_t stream) {
    const float* x  = (const float*)d_in[0];
    // d_in[1] = pH : softmax shift-invariant, ignored
    const float* Wq = (const float*)d_in[2];
    const float* bq = (const float*)d_in[3];
    const float* Wk = (const float*)d_in[4];
    const float* bk = (const float*)d_in[5];
    const float* Wv = (const float*)d_in[6];
    const float* bv = (const float*)d_in[7];
    const float* Wo = (const float*)d_in[8];
    const float* bo = (const float*)d_in[9];
    float* out = (float*)d_out;

    char* ws = (char*)d_ws;
    const size_t MB = 1024 * 1024;
    short* qh  = (short*)(ws + 0 * MB);      // 8 MB
    short* kh  = (short*)(ws + 16 * MB);     // 8 MB
    short* vth = (short*)(ws + 32 * MB);     // 8 MB
    short* aoh = (short*)(ws + 48 * MB);     // 8 MB
    short* xhi = (short*)(ws + 64 * MB);     // 8 MB
    short* wqkv_hi = (short*)(ws + 80 * MB); // 6 MB [3072][1024]
    short* wto_hi  = (short*)(ws + 92 * MB); // 2 MB

    dim3 blk(256);
    const int n8 = MROWS * DMODEL / 8;

    hipLaunchKernelGGL(convert_h, dim3(n8 / 256), blk, 0, stream, x, xhi, n8);
    hipLaunchKernelGGL(transpose_w4, dim3(16, 16, 4), blk, 0, stream,
                       Wq, Wk, Wv, Wo, wqkv_hi, wto_hi);

    const float qscale = 0.125f * 1.44269504088896f;   // fold 1/sqrt(dh)*log2(e)
    hipLaunchKernelGGL(mfma_gemm, dim3(3072 / 128, MROWS / 128), blk, 0, stream,
                       xhi, wqkv_hi, bq, bk, bv,
                       qh, kh, vth, (float*)nullptr, 0, qscale);

    hipLaunchKernelGGL(attn_mfma, dim3(BATCH * NHEADS * (SEQ / 64)), blk, 0, stream,
                       qh, kh, vth, aoh);

    hipLaunchKernelGGL(mfma_gemm, dim3(1024 / 128, MROWS / 128), blk, 0, stream,
                       aoh, wto_hi, bo, bo, bo,
                       (short*)nullptr, (short*)nullptr, (short*)nullptr,
                       out, 1, 1.0f);
}

// Round 9
// 210.402 us; speedup vs baseline: 8.5807x; 1.0296x over previous
//
#include <hip/hip_runtime.h>
#include <hip/hip_bf16.h>
#include <math.h>

// Problem constants
#define BATCH 2
#define SEQ   2048
#define DMODEL 1024
#define NHEADS 16
#define DHEAD 64
#define MROWS (BATCH*SEQ)   // 4096

typedef __attribute__((ext_vector_type(8))) short bf16x8;
typedef __attribute__((ext_vector_type(4))) short bf16x4;
typedef __attribute__((ext_vector_type(4))) float f32x4;

__device__ __forceinline__ short f2bf(float f) {   // RNE float->bf16
    union { float f; unsigned u; } c; c.f = f;
    unsigned r = (c.u + 0x7fffu + ((c.u >> 16) & 1u)) >> 16;
    return (short)r;
}
__device__ __forceinline__ float truncmask(unsigned u) {  // bf16-trunc value as f32
    union { unsigned u; float f; } c; c.u = u & 0xffff0000u;
    return c.f;
}

__device__ __forceinline__ void async_ld16(const void* g, void* l) {
    __builtin_amdgcn_global_load_lds(
        (const __attribute__((address_space(1))) unsigned*)g,
        (__attribute__((address_space(3))) unsigned*)l, 16, 0, 0);
}

// ---------------- convert: fp32 -> bf16 hi (8 elems/thread) ----------------
__global__ __launch_bounds__(256) void convert_h(
    const float* __restrict__ in, short* __restrict__ hi, int n8)
{
    const int i = blockIdx.x * 256 + threadIdx.x;
    if (i >= n8) return;
    const float4* p = (const float4*)in + (size_t)i * 2;
    float4 a = p[0], b = p[1];
    float v[8] = {a.x, a.y, a.z, a.w, b.x, b.y, b.z, b.w};
    bf16x8 H;
    #pragma unroll
    for (int j = 0; j < 8; ++j) H[j] = f2bf(v[j]);
    *((bf16x8*)hi + i) = H;
}

// ---------------- fused transpose+convert, hi only ----------------
__global__ __launch_bounds__(256) void transpose_w4(
    const float* __restrict__ W0, const float* __restrict__ W1,
    const float* __restrict__ W2, const float* __restrict__ W3,
    short* __restrict__ oqkv, short* __restrict__ oo)
{
    __shared__ float T[64][65];
    const int tid = threadIdx.x;
    const int z = blockIdx.z;
    const float* W = (z == 0) ? W0 : (z == 1) ? W1 : (z == 2) ? W2 : W3;
    short* out = (z < 3) ? (oqkv + (size_t)z * 1024 * 1024) : oo;
    const int n0 = blockIdx.x * 64, k0 = blockIdx.y * 64;
    #pragma unroll
    for (int i = 0; i < 16; ++i) {
        const int idx = tid + i * 256;
        const int r = idx >> 6, c = idx & 63;
        T[r][c] = W[(size_t)(k0 + r) * DMODEL + n0 + c];
    }
    __syncthreads();
    #pragma unroll
    for (int i = 0; i < 4; ++i) {
        const int idx = tid + i * 256;
        const int r = idx >> 4, g = idx & 15;
        bf16x4 H;
        #pragma unroll
        for (int j = 0; j < 4; ++j)
            H[j] = f2bf(T[g * 4 + j][r]);
        *(bf16x4*)(out + (size_t)(n0 + r) * DMODEL + k0 + g * 4) = H;
    }
}

// ---------------- MFMA GEMM: C = A[M,K] * Bt[N,K]^T, 1-term bf16 ----------------
// mode 0: q/k bf16 [B,H,S,64], v bf16 transposed [B,H,64,S] — all stores routed
//         through per-wave LDS scratch (aliased on Ah/Bh) for coalesced b128.
// mode 1: row-major fp32 [M,1024] + bias
#define GBK 64

__global__ __launch_bounds__(256) void mfma_gemm(
    const short* __restrict__ Ahi, const short* __restrict__ Bthi,
    const float* __restrict__ b0, const float* __restrict__ b1, const float* __restrict__ b2,
    short* __restrict__ oqh, short* __restrict__ okh, short* __restrict__ ovh,
    float* __restrict__ outf, int mode, float qscale)
{
    __shared__ short Ah[128 * GBK], Bh[128 * GBK];   // 16 KB each

    const int tid  = threadIdx.x;
    const int lane = tid & 63;
    const int w    = tid >> 6;
    const int quad = lane >> 4;
    const int l15  = lane & 15;
    const int wr   = w >> 1, wc = w & 1;
    const int m0   = blockIdx.y * 128;
    const int n0   = blockIdx.x * 128;
    const int K    = DMODEL;

    f32x4 acc[4][4] = {};

    int srow[4], spos[4];
    #pragma unroll
    for (int j = 0; j < 4; ++j) {
        const int c = w * 256 + j * 64 + lane;
        srow[j] = c >> 3;
        spos[j] = (c & 7) ^ (srow[j] & 7);
    }

    for (int k0 = 0; k0 < K; k0 += GBK) {
        __syncthreads();
        #pragma unroll
        for (int j = 0; j < 4; ++j) {
            const int cB = (w * 256 + j * 64) * 8;
            async_ld16(Ahi + (size_t)(m0 + srow[j]) * K + k0 + spos[j] * 8, Ah + cB);
            async_ld16(Bthi + (size_t)(n0 + srow[j]) * K + k0 + spos[j] * 8, Bh + cB);
        }
        __syncthreads();

        #pragma unroll
        for (int s = 0; s < 2; ++s) {
            bf16x8 afh[4], bfh[4];
            #pragma unroll
            for (int mi = 0; mi < 4; ++mi) {
                const int row = wr * 64 + mi * 16 + l15;
                const int pos = (s * 4 + quad) ^ (row & 7);
                afh[mi] = *(const bf16x8*)(Ah + row * GBK + pos * 8);
            }
            #pragma unroll
            for (int ni = 0; ni < 4; ++ni) {
                const int row = wc * 64 + ni * 16 + l15;
                const int pos = (s * 4 + quad) ^ (row & 7);
                bfh[ni] = *(const bf16x8*)(Bh + row * GBK + pos * 8);
            }
            #pragma unroll
            for (int mi = 0; mi < 4; ++mi)
                #pragma unroll
                for (int ni = 0; ni < 4; ++ni)
                    acc[mi][ni] = __builtin_amdgcn_mfma_f32_16x16x32_bf16(
                        afh[mi], bfh[ni], acc[mi][ni], 0, 0, 0);
        }
    }

    const int nbase = n0 + wc * 64;
    if (mode == 1) {
        #pragma unroll
        for (int mi = 0; mi < 4; ++mi)
            #pragma unroll
            for (int ni = 0; ni < 4; ++ni)
                #pragma unroll
                for (int r = 0; r < 4; ++r) {
                    const int m = m0 + wr * 64 + mi * 16 + quad * 4 + r;
                    const int nn = nbase + ni * 16 + l15;
                    outf[(size_t)m * DMODEL + nn] = acc[mi][ni][r] + b0[nn];
                }
    } else {
        __syncthreads();   // all waves done reading Ah/Bh; reuse as scratch
        short* scr = (w < 2) ? (Ah + w * 4096) : (Bh + (w - 2) * 4096);  // 8 KB/wave
        const int which = nbase >> 10;               // 0=q, 1=k, 2=v (wave-uniform)
        const int hh = (nbase & 1023) >> 6;          // head (n-range = one head)
        const int mb = m0 + wr * 64;
        const int b = mb >> 11, sbase = mb & (SEQ - 1);

        if (which < 2) {
            const float* bias = which ? b1 : b0;
            short* dstp = which ? okh : oqh;
            const float scl = which ? 1.0f : qscale;
            // scratch[s][d], 64x64, XOR-8 chunk swizzle per row
            #pragma unroll
            for (int mi = 0; mi < 4; ++mi)
                #pragma unroll
                for (int ni = 0; ni < 4; ++ni)
                    #pragma unroll
                    for (int r = 0; r < 4; ++r) {
                        const int sloc = mi * 16 + quad * 4 + r;
                        const int dloc = ni * 16 + l15;
                        const int nn = (nbase + ni * 16 + l15) & 1023;
                        scr[sloc * 64 + (((dloc >> 3) ^ (sloc & 7)) * 8) + (dloc & 7)] =
                            f2bf((acc[mi][ni][r] + bias[nn]) * scl);
                    }
            // wave-private scratch: in-order DS, no barrier
            #pragma unroll
            for (int i = 0; i < 8; ++i) {
                const int sloc = i * 8 + (lane >> 3);
                const int cph = (lane & 7) ^ (sloc & 7);
                bf16x8 row = *(const bf16x8*)(scr + sloc * 64 + cph * 8);
                const int dloc = (lane & 7) * 8;
                *(bf16x8*)(dstp + ((size_t)(b * NHEADS + hh) * SEQ + sbase + sloc) * DHEAD + dloc) = row;
            }
        } else {
            // scratch[d][s] (transposed), 64x64, XOR-8 chunk swizzle per row
            #pragma unroll
            for (int mi = 0; mi < 4; ++mi)
                #pragma unroll
                for (int ni = 0; ni < 4; ++ni)
                    #pragma unroll
                    for (int r = 0; r < 4; ++r) {
                        const int sloc = mi * 16 + quad * 4 + r;
                        const int dloc = ni * 16 + l15;
                        const int nn = (nbase + ni * 16 + l15) & 1023;
                        scr[dloc * 64 + (((sloc >> 3) ^ (dloc & 7)) * 8) + (sloc & 7)] =
                            f2bf(acc[mi][ni][r] + b2[nn]);
                    }
            #pragma unroll
            for (int i = 0; i < 8; ++i) {
                const int dloc = i * 8 + (lane >> 3);
                const int cph = (lane & 7) ^ (dloc & 7);
                bf16x8 row = *(const bf16x8*)(scr + dloc * 64 + cph * 8);
                const int sg = sbase + (lane & 7) * 8;
                *(bf16x8*)(ovh + ((size_t)(b * NHEADS + hh) * DHEAD + dloc) * SEQ + sg) = row;
            }
        }
    }
}

// ---------------- MFMA flash attention v7 ----------------
// 32 q per wave (two 16-q fragments share every K/V LDS fragment read),
// 128 q per block, grid 512. S^T = K*Q^T; P via v_perm truncation; raw v_exp.
// XCD-local head mapping (bh = blk&31).
#define PP 72

__global__ __launch_bounds__(256) void attn_mfma(
    const short* __restrict__ Qh_g, const short* __restrict__ Kh_g,
    const short* __restrict__ Vth_g, short* __restrict__ Oh_g)
{
    __shared__ short Ksh[4096];          // [key][d] 64x64, swizzled
    __shared__ short Vsh[4096];          // [d][s]  64x64, swizzled
    __shared__ short Ph[4][2][16 * PP];  // per-wave, per-qfrag P tiles

    const int tid  = threadIdx.x;
    const int lane = tid & 63;
    const int w    = tid >> 6;
    const int quad = lane >> 4;
    const int l15  = lane & 15;

    const int bh    = blockIdx.x & 31;       // XCD-local head
    const int qtile = blockIdx.x >> 5;       // 0..15
    const int q0    = qtile * 128 + w * 32;
    const size_t kvb = (size_t)bh * SEQ * DHEAD;

    bf16x8 qA[2], qB[2];
    {
        const size_t qrA = kvb + (size_t)(q0 + l15) * DHEAD;
        const size_t qrB = kvb + (size_t)(q0 + 16 + l15) * DHEAD;
        qA[0] = *(const bf16x8*)(Qh_g + qrA + quad * 8);
        qA[1] = *(const bf16x8*)(Qh_g + qrA + 32 + quad * 8);
        qB[0] = *(const bf16x8*)(Qh_g + qrB + quad * 8);
        qB[1] = *(const bf16x8*)(Qh_g + qrB + 32 + quad * 8);
    }

    short* dst = (w < 2) ? Ksh : Vsh;
    const bool isv = (w >= 2);
    int srow[4], spos[4];
    #pragma unroll
    for (int j = 0; j < 4; ++j) {
        const int c = (w & 1) * 256 + j * 64 + lane;
        srow[j] = c >> 3;
        spos[j] = (c & 7) ^ (srow[j] & 7);
    }

    f32x4 oA[4] = {}, oB[4] = {};
    float lA = 0.f, lB = 0.f;

    for (int kb = 0; kb < SEQ; kb += 64) {
        __syncthreads();
        {
            const short* src = isv ? (Vth_g + kvb + kb) : (Kh_g + kvb + (size_t)kb * DHEAD);
            #pragma unroll
            for (int j = 0; j < 4; ++j) {
                const short* g = src + (isv ? ((size_t)srow[j] * SEQ + spos[j] * 8)
                                            : ((size_t)srow[j] * DHEAD + spos[j] * 8));
                async_ld16(g, dst + ((w & 1) * 256 + j * 64) * 8);
            }
        }
        __syncthreads();

        // ---- S^T = K Q^T for both q-fragments (K frags read once) ----
        #pragma unroll
        for (int mf = 0; mf < 4; ++mf) {
            const int row = mf * 16 + l15;
            const int sw = row & 7;
            bf16x8 kh0 = *(const bf16x8*)(Ksh + row * 64 + ((quad ^ sw) * 8));
            bf16x8 kh1 = *(const bf16x8*)(Ksh + row * 64 + (((4 + quad) ^ sw) * 8));
            f32x4 cA = {}, cB = {};
            cA = __builtin_amdgcn_mfma_f32_16x16x32_bf16(kh0, qA[0], cA, 0, 0, 0);
            cA = __builtin_amdgcn_mfma_f32_16x16x32_bf16(kh1, qA[1], cA, 0, 0, 0);
            cB = __builtin_amdgcn_mfma_f32_16x16x32_bf16(kh0, qB[0], cB, 0, 0, 0);
            cB = __builtin_amdgcn_mfma_f32_16x16x32_bf16(kh1, qB[1], cB, 0, 0, 0);

            unsigned uA[4], uB[4];
            #pragma unroll
            for (int r = 0; r < 4; ++r) {
                union { float f; unsigned u; } p;
                p.f = __builtin_amdgcn_exp2f(cA[r]);
                uA[r] = p.u; lA += truncmask(uA[r]);
                p.f = __builtin_amdgcn_exp2f(cB[r]);
                uB[r] = p.u; lB += truncmask(uB[r]);
            }
            uint2 pkA, pkB;
            pkA.x = __builtin_amdgcn_perm(uA[1], uA[0], 0x07060302u);
            pkA.y = __builtin_amdgcn_perm(uA[3], uA[2], 0x07060302u);
            pkB.x = __builtin_amdgcn_perm(uB[1], uB[0], 0x07060302u);
            pkB.y = __builtin_amdgcn_perm(uB[3], uB[2], 0x07060302u);
            *(uint2*)(&Ph[w][0][l15 * PP + mf * 16 + quad * 4]) = pkA;
            *(uint2*)(&Ph[w][1][l15 * PP + mf * 16 + quad * 4]) = pkB;
        }
        // wave-private LDS: in-order within wave, no barrier needed

        bf16x8 pA0 = *(const bf16x8*)(&Ph[w][0][l15 * PP + quad * 8]);
        bf16x8 pA1 = *(const bf16x8*)(&Ph[w][0][l15 * PP + 32 + quad * 8]);
        bf16x8 pB0 = *(const bf16x8*)(&Ph[w][1][l15 * PP + quad * 8]);
        bf16x8 pB1 = *(const bf16x8*)(&Ph[w][1][l15 * PP + 32 + quad * 8]);

        // ---- O += P V for both fragments (V frags read once) ----
        #pragma unroll
        for (int nf = 0; nf < 4; ++nf) {
            const int row = nf * 16 + l15;
            const int sw = row & 7;
            bf16x8 vh0 = *(const bf16x8*)(Vsh + row * 64 + ((quad ^ sw) * 8));
            bf16x8 vh1 = *(const bf16x8*)(Vsh + row * 64 + (((4 + quad) ^ sw) * 8));
            f32x4 cA = oA[nf], cB = oB[nf];
            cA = __builtin_amdgcn_mfma_f32_16x16x32_bf16(pA0, vh0, cA, 0, 0, 0);
            cA = __builtin_amdgcn_mfma_f32_16x16x32_bf16(pA1, vh1, cA, 0, 0, 0);
            cB = __builtin_amdgcn_mfma_f32_16x16x32_bf16(pB0, vh0, cB, 0, 0, 0);
            cB = __builtin_amdgcn_mfma_f32_16x16x32_bf16(pB1, vh1, cB, 0, 0, 0);
            oA[nf] = cA; oB[nf] = cB;
        }
    }

    // ---- epilogue ----
    float lsA = lA, lsB = lB;
    lsA += __shfl_xor(lsA, 16, 64);  lsA += __shfl_xor(lsA, 32, 64);
    lsB += __shfl_xor(lsB, 16, 64);  lsB += __shfl_xor(lsB, 32, 64);
    float liA[4], liB[4];
    #pragma unroll
    for (int r = 0; r < 4; ++r) {
        liA[r] = 1.0f / __shfl(lsA, quad * 4 + r, 64);
        liB[r] = 1.0f / __shfl(lsB, quad * 4 + r, 64);
    }

    const int b = bh >> 4, hh = bh & 15;
    #pragma unroll
    for (int nf = 0; nf < 4; ++nf) {
        #pragma unroll
        for (int r = 0; r < 4; ++r) {
            const int qa = q0 + quad * 4 + r;
            const int d = nf * 16 + l15;
            Oh_g[(size_t)(b * SEQ + qa) * DMODEL + hh * DHEAD + d] = f2bf(oA[nf][r] * liA[r]);
            Oh_g[(size_t)(b * SEQ + qa + 16) * DMODEL + hh * DHEAD + d] = f2bf(oB[nf][r] * liB[r]);
        }
    }
}

// ---------------- launch ----------------
extern "C" void kernel_launch(void* const* d_in, const int* in_sizes, int n_in,
                              void* d_out, int out_size, void* d_ws, size_t ws_size,
                              hipStream_t stream) {
    const float* x  = (const float*)d_in[0];
    // d_in[1] = pH : softmax shift-invariant, ignored
    const float* Wq = (const float*)d_in[2];
    const float* bq = (const float*)d_in[3];
    const float* Wk = (const float*)d_in[4];
    const float* bk = (const float*)d_in[5];
    const float* Wv = (const float*)d_in[6];
    const float* bv = (const float*)d_in[7];
    const float* Wo = (const float*)d_in[8];
    const float* bo = (const float*)d_in[9];
    float* out = (float*)d_out;

    char* ws = (char*)d_ws;
    const size_t MB = 1024 * 1024;
    short* qh  = (short*)(ws + 0 * MB);      // 8 MB
    short* kh  = (short*)(ws + 16 * MB);     // 8 MB
    short* vth = (short*)(ws + 32 * MB);     // 8 MB
    short* aoh = (short*)(ws + 48 * MB);     // 8 MB
    short* xhi = (short*)(ws + 64 * MB);     // 8 MB
    short* wqkv_hi = (short*)(ws + 80 * MB); // 6 MB [3072][1024]
    short* wto_hi  = (short*)(ws + 92 * MB); // 2 MB

    dim3 blk(256);
    const int n8 = MROWS * DMODEL / 8;

    hipLaunchKernelGGL(convert_h, dim3(n8 / 256), blk, 0, stream, x, xhi, n8);
    hipLaunchKernelGGL(transpose_w4, dim3(16, 16, 4), blk, 0, stream,
                       Wq, Wk, Wv, Wo, wqkv_hi, wto_hi);

    const float qscale = 0.125f * 1.44269504088896f;   // fold 1/sqrt(dh)*log2(e)
    hipLaunchKernelGGL(mfma_gemm, dim3(3072 / 128, MROWS / 128), blk, 0, stream,
                       xhi, wqkv_hi, bq, bk, bv,
                       qh, kh, vth, (float*)nullptr, 0, qscale);

    hipLaunchKernelGGL(attn_mfma, dim3(BATCH * NHEADS * (SEQ / 128)), blk, 0, stream,
                       qh, kh, vth, aoh);

    hipLaunchKernelGGL(mfma_gemm, dim3(1024 / 128, MROWS / 128), blk, 0, stream,
                       aoh, wto_hi, bo, bo, bo,
                       (short*)nullptr, (short*)nullptr, (short*)nullptr,
                       out, 1, 1.0f);
}

// Round 10
// 208.828 us; speedup vs baseline: 8.6454x; 1.0075x over previous
//
#include <hip/hip_runtime.h>
#include <hip/hip_bf16.h>
#include <math.h>

// Problem constants
#define BATCH 2
#define SEQ   2048
#define DMODEL 1024
#define NHEADS 16
#define DHEAD 64
#define MROWS (BATCH*SEQ)   // 4096

typedef __attribute__((ext_vector_type(8))) short bf16x8;
typedef __attribute__((ext_vector_type(4))) short bf16x4;
typedef __attribute__((ext_vector_type(4))) float f32x4;

__device__ __forceinline__ short f2bf(float f) {   // RNE float->bf16
    union { float f; unsigned u; } c; c.f = f;
    unsigned r = (c.u + 0x7fffu + ((c.u >> 16) & 1u)) >> 16;
    return (short)r;
}

__device__ __forceinline__ void async_ld16(const void* g, void* l) {
    __builtin_amdgcn_global_load_lds(
        (const __attribute__((address_space(1))) unsigned*)g,
        (__attribute__((address_space(3))) unsigned*)l, 16, 0, 0);
}

// ---------------- convert: fp32 -> bf16 hi (8 elems/thread) ----------------
__global__ __launch_bounds__(256) void convert_h(
    const float* __restrict__ in, short* __restrict__ hi, int n8)
{
    const int i = blockIdx.x * 256 + threadIdx.x;
    if (i >= n8) return;
    const float4* p = (const float4*)in + (size_t)i * 2;
    float4 a = p[0], b = p[1];
    float v[8] = {a.x, a.y, a.z, a.w, b.x, b.y, b.z, b.w};
    bf16x8 H;
    #pragma unroll
    for (int j = 0; j < 8; ++j) H[j] = f2bf(v[j]);
    *((bf16x8*)hi + i) = H;
}

// ---------------- fused transpose+convert, hi only ----------------
__global__ __launch_bounds__(256) void transpose_w4(
    const float* __restrict__ W0, const float* __restrict__ W1,
    const float* __restrict__ W2, const float* __restrict__ W3,
    short* __restrict__ oqkv, short* __restrict__ oo)
{
    __shared__ float T[64][65];
    const int tid = threadIdx.x;
    const int z = blockIdx.z;
    const float* W = (z == 0) ? W0 : (z == 1) ? W1 : (z == 2) ? W2 : W3;
    short* out = (z < 3) ? (oqkv + (size_t)z * 1024 * 1024) : oo;
    const int n0 = blockIdx.x * 64, k0 = blockIdx.y * 64;
    #pragma unroll
    for (int i = 0; i < 16; ++i) {
        const int idx = tid + i * 256;
        const int r = idx >> 6, c = idx & 63;
        T[r][c] = W[(size_t)(k0 + r) * DMODEL + n0 + c];
    }
    __syncthreads();
    #pragma unroll
    for (int i = 0; i < 4; ++i) {
        const int idx = tid + i * 256;
        const int r = idx >> 4, g = idx & 15;
        bf16x4 H;
        #pragma unroll
        for (int j = 0; j < 4; ++j)
            H[j] = f2bf(T[g * 4 + j][r]);
        *(bf16x4*)(out + (size_t)(n0 + r) * DMODEL + k0 + g * 4) = H;
    }
}

// ---------------- MFMA GEMM: C = A[M,K] * Bt[N,K]^T, 1-term bf16 ----------------
// mode 0: q/k bf16 [B,H,S,64], v bf16 transposed [B,H,64,S] — stores routed
//         through per-wave LDS scratch (aliased on Ah/Bh) for coalesced b128.
// mode 1: row-major fp32 [M,1024] + bias
#define GBK 64

__global__ __launch_bounds__(256) void mfma_gemm(
    const short* __restrict__ Ahi, const short* __restrict__ Bthi,
    const float* __restrict__ b0, const float* __restrict__ b1, const float* __restrict__ b2,
    short* __restrict__ oqh, short* __restrict__ okh, short* __restrict__ ovh,
    float* __restrict__ outf, int mode, float qscale)
{
    __shared__ short Ah[128 * GBK], Bh[128 * GBK];   // 16 KB each

    const int tid  = threadIdx.x;
    const int lane = tid & 63;
    const int w    = tid >> 6;
    const int quad = lane >> 4;
    const int l15  = lane & 15;
    const int wr   = w >> 1, wc = w & 1;
    const int m0   = blockIdx.y * 128;
    const int n0   = blockIdx.x * 128;
    const int K    = DMODEL;

    f32x4 acc[4][4] = {};

    int srow[4], spos[4];
    #pragma unroll
    for (int j = 0; j < 4; ++j) {
        const int c = w * 256 + j * 64 + lane;
        srow[j] = c >> 3;
        spos[j] = (c & 7) ^ (srow[j] & 7);
    }

    for (int k0 = 0; k0 < K; k0 += GBK) {
        __syncthreads();
        #pragma unroll
        for (int j = 0; j < 4; ++j) {
            const int cB = (w * 256 + j * 64) * 8;
            async_ld16(Ahi + (size_t)(m0 + srow[j]) * K + k0 + spos[j] * 8, Ah + cB);
            async_ld16(Bthi + (size_t)(n0 + srow[j]) * K + k0 + spos[j] * 8, Bh + cB);
        }
        __syncthreads();

        #pragma unroll
        for (int s = 0; s < 2; ++s) {
            bf16x8 afh[4], bfh[4];
            #pragma unroll
            for (int mi = 0; mi < 4; ++mi) {
                const int row = wr * 64 + mi * 16 + l15;
                const int pos = (s * 4 + quad) ^ (row & 7);
                afh[mi] = *(const bf16x8*)(Ah + row * GBK + pos * 8);
            }
            #pragma unroll
            for (int ni = 0; ni < 4; ++ni) {
                const int row = wc * 64 + ni * 16 + l15;
                const int pos = (s * 4 + quad) ^ (row & 7);
                bfh[ni] = *(const bf16x8*)(Bh + row * GBK + pos * 8);
            }
            #pragma unroll
            for (int mi = 0; mi < 4; ++mi)
                #pragma unroll
                for (int ni = 0; ni < 4; ++ni)
                    acc[mi][ni] = __builtin_amdgcn_mfma_f32_16x16x32_bf16(
                        afh[mi], bfh[ni], acc[mi][ni], 0, 0, 0);
        }
    }

    const int nbase = n0 + wc * 64;
    if (mode == 1) {
        #pragma unroll
        for (int mi = 0; mi < 4; ++mi)
            #pragma unroll
            for (int ni = 0; ni < 4; ++ni)
                #pragma unroll
                for (int r = 0; r < 4; ++r) {
                    const int m = m0 + wr * 64 + mi * 16 + quad * 4 + r;
                    const int nn = nbase + ni * 16 + l15;
                    outf[(size_t)m * DMODEL + nn] = acc[mi][ni][r] + b0[nn];
                }
    } else {
        __syncthreads();   // all waves done reading Ah/Bh; reuse as scratch
        short* scr = (w < 2) ? (Ah + w * 4096) : (Bh + (w - 2) * 4096);  // 8 KB/wave
        const int which = nbase >> 10;               // 0=q, 1=k, 2=v (wave-uniform)
        const int hh = (nbase & 1023) >> 6;          // head (n-range = one head)
        const int mb = m0 + wr * 64;
        const int b = mb >> 11, sbase = mb & (SEQ - 1);

        if (which < 2) {
            const float* bias = which ? b1 : b0;
            short* dstp = which ? okh : oqh;
            const float scl = which ? 1.0f : qscale;
            #pragma unroll
            for (int mi = 0; mi < 4; ++mi)
                #pragma unroll
                for (int ni = 0; ni < 4; ++ni)
                    #pragma unroll
                    for (int r = 0; r < 4; ++r) {
                        const int sloc = mi * 16 + quad * 4 + r;
                        const int dloc = ni * 16 + l15;
                        const int nn = (nbase + ni * 16 + l15) & 1023;
                        scr[sloc * 64 + (((dloc >> 3) ^ (sloc & 7)) * 8) + (dloc & 7)] =
                            f2bf((acc[mi][ni][r] + bias[nn]) * scl);
                    }
            #pragma unroll
            for (int i = 0; i < 8; ++i) {
                const int sloc = i * 8 + (lane >> 3);
                const int cph = (lane & 7) ^ (sloc & 7);
                bf16x8 row = *(const bf16x8*)(scr + sloc * 64 + cph * 8);
                const int dloc = (lane & 7) * 8;
                *(bf16x8*)(dstp + ((size_t)(b * NHEADS + hh) * SEQ + sbase + sloc) * DHEAD + dloc) = row;
            }
        } else {
            #pragma unroll
            for (int mi = 0; mi < 4; ++mi)
                #pragma unroll
                for (int ni = 0; ni < 4; ++ni)
                    #pragma unroll
                    for (int r = 0; r < 4; ++r) {
                        const int sloc = mi * 16 + quad * 4 + r;
                        const int dloc = ni * 16 + l15;
                        const int nn = (nbase + ni * 16 + l15) & 1023;
                        scr[dloc * 64 + (((sloc >> 3) ^ (dloc & 7)) * 8) + (sloc & 7)] =
                            f2bf(acc[mi][ni][r] + b2[nn]);
                    }
            #pragma unroll
            for (int i = 0; i < 8; ++i) {
                const int dloc = i * 8 + (lane >> 3);
                const int cph = (lane & 7) ^ (dloc & 7);
                bf16x8 row = *(const bf16x8*)(scr + dloc * 64 + cph * 8);
                const int sg = sbase + (lane & 7) * 8;
                *(bf16x8*)(ovh + ((size_t)(b * NHEADS + hh) * DHEAD + dloc) * SEQ + sg) = row;
            }
        }
    }
}

// ---------------- MFMA flash attention v8 ----------------
// 32 q/wave, 128 q/block, grid 512. S^T = K*Q^T; P via v_perm truncation;
// raw v_exp. l = P·ones via MFMA (exact sum of the truncated P values ->
// truncation bias still cancels; lands in O's row layout, no shuffles).
// Double-buffered K/V staging: one barrier per iter, DMA overlaps compute.
#define PP 72

__global__ __launch_bounds__(256) void attn_mfma(
    const short* __restrict__ Qh_g, const short* __restrict__ Kh_g,
    const short* __restrict__ Vth_g, short* __restrict__ Oh_g)
{
    __shared__ short Ksh[2][4096];       // [buf][key*64+d swizzled]
    __shared__ short Vsh[2][4096];       // [buf][d*64+s swizzled]
    __shared__ short Ph[4][2][16 * PP];  // per-wave, per-qfrag P tiles

    const int tid  = threadIdx.x;
    const int lane = tid & 63;
    const int w    = tid >> 6;
    const int quad = lane >> 4;
    const int l15  = lane & 15;

    const int bh    = blockIdx.x & 31;       // XCD-local head
    const int qtile = blockIdx.x >> 5;       // 0..15
    const int q0    = qtile * 128 + w * 32;
    const size_t kvb = (size_t)bh * SEQ * DHEAD;

    bf16x8 ones;
    #pragma unroll
    for (int j = 0; j < 8; ++j) ones[j] = (short)0x3f80;   // bf16 1.0

    bf16x8 qA[2], qB[2];
    {
        const size_t qrA = kvb + (size_t)(q0 + l15) * DHEAD;
        const size_t qrB = kvb + (size_t)(q0 + 16 + l15) * DHEAD;
        qA[0] = *(const bf16x8*)(Qh_g + qrA + quad * 8);
        qA[1] = *(const bf16x8*)(Qh_g + qrA + 32 + quad * 8);
        qB[0] = *(const bf16x8*)(Qh_g + qrB + quad * 8);
        qB[1] = *(const bf16x8*)(Qh_g + qrB + 32 + quad * 8);
    }

    const bool isv = (w >= 2);
    int srow[4], spos[4];
    #pragma unroll
    for (int j = 0; j < 4; ++j) {
        const int c = (w & 1) * 256 + j * 64 + lane;
        srow[j] = c >> 3;
        spos[j] = (c & 7) ^ (srow[j] & 7);
    }

    auto stage = [&](int buf, int kb) {
        short* d = isv ? Vsh[buf] : Ksh[buf];
        const short* src = isv ? (Vth_g + kvb + kb) : (Kh_g + kvb + (size_t)kb * DHEAD);
        #pragma unroll
        for (int j = 0; j < 4; ++j) {
            const short* g = src + (isv ? ((size_t)srow[j] * SEQ + spos[j] * 8)
                                        : ((size_t)srow[j] * DHEAD + spos[j] * 8));
            async_ld16(g, d + ((w & 1) * 256 + j * 64) * 8);
        }
    };

    f32x4 oA[4] = {}, oB[4] = {};
    f32x4 lAv = {}, lBv = {};

    stage(0, 0);
    int pb = 0;
    for (int kb = 0; kb < SEQ; kb += 64, pb ^= 1) {
        __syncthreads();   // prefetch of buf pb drained; prior reads of pb^1 done
        if (kb + 64 < SEQ) stage(pb ^ 1, kb + 64);

        const short* Kb = Ksh[pb];
        const short* Vb = Vsh[pb];

        // ---- S^T = K Q^T for both q-fragments (K frags read once) ----
        #pragma unroll
        for (int mf = 0; mf < 4; ++mf) {
            const int row = mf * 16 + l15;
            const int sw = row & 7;
            bf16x8 kh0 = *(const bf16x8*)(Kb + row * 64 + ((quad ^ sw) * 8));
            bf16x8 kh1 = *(const bf16x8*)(Kb + row * 64 + (((4 + quad) ^ sw) * 8));
            f32x4 cA = {}, cB = {};
            cA = __builtin_amdgcn_mfma_f32_16x16x32_bf16(kh0, qA[0], cA, 0, 0, 0);
            cA = __builtin_amdgcn_mfma_f32_16x16x32_bf16(kh1, qA[1], cA, 0, 0, 0);
            cB = __builtin_amdgcn_mfma_f32_16x16x32_bf16(kh0, qB[0], cB, 0, 0, 0);
            cB = __builtin_amdgcn_mfma_f32_16x16x32_bf16(kh1, qB[1], cB, 0, 0, 0);

            unsigned uA[4], uB[4];
            #pragma unroll
            for (int r = 0; r < 4; ++r) {
                union { float f; unsigned u; } p;
                p.f = __builtin_amdgcn_exp2f(cA[r]);
                uA[r] = p.u;
                p.f = __builtin_amdgcn_exp2f(cB[r]);
                uB[r] = p.u;
            }
            uint2 pkA, pkB;
            pkA.x = __builtin_amdgcn_perm(uA[1], uA[0], 0x07060302u);
            pkA.y = __builtin_amdgcn_perm(uA[3], uA[2], 0x07060302u);
            pkB.x = __builtin_amdgcn_perm(uB[1], uB[0], 0x07060302u);
            pkB.y = __builtin_amdgcn_perm(uB[3], uB[2], 0x07060302u);
            *(uint2*)(&Ph[w][0][l15 * PP + mf * 16 + quad * 4]) = pkA;
            *(uint2*)(&Ph[w][1][l15 * PP + mf * 16 + quad * 4]) = pkB;
        }
        // wave-private LDS: in-order within wave, no barrier needed

        bf16x8 pA0 = *(const bf16x8*)(&Ph[w][0][l15 * PP + quad * 8]);
        bf16x8 pA1 = *(const bf16x8*)(&Ph[w][0][l15 * PP + 32 + quad * 8]);
        bf16x8 pB0 = *(const bf16x8*)(&Ph[w][1][l15 * PP + quad * 8]);
        bf16x8 pB1 = *(const bf16x8*)(&Ph[w][1][l15 * PP + 32 + quad * 8]);

        // ---- l += P * ones (exact sum of truncated P; row-aligned with O) ----
        lAv = __builtin_amdgcn_mfma_f32_16x16x32_bf16(pA0, ones, lAv, 0, 0, 0);
        lAv = __builtin_amdgcn_mfma_f32_16x16x32_bf16(pA1, ones, lAv, 0, 0, 0);
        lBv = __builtin_amdgcn_mfma_f32_16x16x32_bf16(pB0, ones, lBv, 0, 0, 0);
        lBv = __builtin_amdgcn_mfma_f32_16x16x32_bf16(pB1, ones, lBv, 0, 0, 0);

        // ---- O += P V for both fragments (V frags read once) ----
        #pragma unroll
        for (int nf = 0; nf < 4; ++nf) {
            const int row = nf * 16 + l15;
            const int sw = row & 7;
            bf16x8 vh0 = *(const bf16x8*)(Vb + row * 64 + ((quad ^ sw) * 8));
            bf16x8 vh1 = *(const bf16x8*)(Vb + row * 64 + (((4 + quad) ^ sw) * 8));
            f32x4 cA = oA[nf], cB = oB[nf];
            cA = __builtin_amdgcn_mfma_f32_16x16x32_bf16(pA0, vh0, cA, 0, 0, 0);
            cA = __builtin_amdgcn_mfma_f32_16x16x32_bf16(pA1, vh1, cA, 0, 0, 0);
            cB = __builtin_amdgcn_mfma_f32_16x16x32_bf16(pB0, vh0, cB, 0, 0, 0);
            cB = __builtin_amdgcn_mfma_f32_16x16x32_bf16(pB1, vh1, cB, 0, 0, 0);
            oA[nf] = cA; oB[nf] = cB;
        }
    }

    // ---- epilogue: l already per-lane in O row layout ----
    float liA[4], liB[4];
    #pragma unroll
    for (int r = 0; r < 4; ++r) {
        liA[r] = 1.0f / lAv[r];
        liB[r] = 1.0f / lBv[r];
    }

    const int b = bh >> 4, hh = bh & 15;
    #pragma unroll
    for (int nf = 0; nf < 4; ++nf) {
        #pragma unroll
        for (int r = 0; r < 4; ++r) {
            const int qa = q0 + quad * 4 + r;
            const int d = nf * 16 + l15;
            Oh_g[(size_t)(b * SEQ + qa) * DMODEL + hh * DHEAD + d] = f2bf(oA[nf][r] * liA[r]);
            Oh_g[(size_t)(b * SEQ + qa + 16) * DMODEL + hh * DHEAD + d] = f2bf(oB[nf][r] * liB[r]);
        }
    }
}

// ---------------- launch ----------------
extern "C" void kernel_launch(void* const* d_in, const int* in_sizes, int n_in,
                              void* d_out, int out_size, void* d_ws, size_t ws_size,
                              hipStream_t stream) {
    const float* x  = (const float*)d_in[0];
    // d_in[1] = pH : softmax shift-invariant, ignored
    const float* Wq = (const float*)d_in[2];
    const float* bq = (const float*)d_in[3];
    const float* Wk = (const float*)d_in[4];
    const float* bk = (const float*)d_in[5];
    const float* Wv = (const float*)d_in[6];
    const float* bv = (const float*)d_in[7];
    const float* Wo = (const float*)d_in[8];
    const float* bo = (const float*)d_in[9];
    float* out = (float*)d_out;

    char* ws = (char*)d_ws;
    const size_t MB = 1024 * 1024;
    short* qh  = (short*)(ws + 0 * MB);      // 8 MB
    short* kh  = (short*)(ws + 16 * MB);     // 8 MB
    short* vth = (short*)(ws + 32 * MB);     // 8 MB
    short* aoh = (short*)(ws + 48 * MB);     // 8 MB
    short* xhi = (short*)(ws + 64 * MB);     // 8 MB
    short* wqkv_hi = (short*)(ws + 80 * MB); // 6 MB [3072][1024]
    short* wto_hi  = (short*)(ws + 92 * MB); // 2 MB

    dim3 blk(256);
    const int n8 = MROWS * DMODEL / 8;

    hipLaunchKernelGGL(convert_h, dim3(n8 / 256), blk, 0, stream, x, xhi, n8);
    hipLaunchKernelGGL(transpose_w4, dim3(16, 16, 4), blk, 0, stream,
                       Wq, Wk, Wv, Wo, wqkv_hi, wto_hi);

    const float qscale = 0.125f * 1.44269504088896f;   // fold 1/sqrt(dh)*log2(e)
    hipLaunchKernelGGL(mfma_gemm, dim3(3072 / 128, MROWS / 128), blk, 0, stream,
                       xhi, wqkv_hi, bq, bk, bv,
                       qh, kh, vth, (float*)nullptr, 0, qscale);

    hipLaunchKernelGGL(attn_mfma, dim3(BATCH * NHEADS * (SEQ / 128)), blk, 0, stream,
                       qh, kh, vth, aoh);

    hipLaunchKernelGGL(mfma_gemm, dim3(1024 / 128, MROWS / 128), blk, 0, stream,
                       aoh, wto_hi, bo, bo, bo,
                       (short*)nullptr, (short*)nullptr, (short*)nullptr,
                       out, 1, 1.0f);
}